// Round 10
// baseline (912.819 us; speedup 1.0000x reference)
//
#include <hip/hip_runtime.h>

#define NXg 432
#define NYg 496
#define SCELLS (NXg*NYg)   // 214272
#define PB 6000
#define NPTS 4096
#define DD 64
#define MM 1024
#define KK 4
#define BB 2
#define NROWS (PB*KK)      // 24000
#define NSEG 16
#define SEGPTS (NPTS/NSEG) // 256 points per segment
#define CHROWS 64          // point rows staged per LDS chunk
#define NCHNK (SEGPTS/CHROWS) // 4 chunks
#define MOP 6              // pillars per k_moG block
#define SHRINK_TH 0.0025f
#define BN_EPS 1e-3f
#define NEG_INF -3.402823466e38f

// sorted-descending top-4 insert on NAMED scalars; caller guarantees v > v3.
// Scans are ascending-index, so strict > keeps earliest index on ties.
#define INS4(v, id, v0,v1,v2,v3, i0,i1,i2,i3) { \
    bool g0 = (v) > v0, g1 = (v) > v1, g2 = (v) > v2; \
    v3 = g2 ? v2 : (v);              i3 = g2 ? i2 : (id); \
    v2 = g2 ? (g1 ? v1 : (v)) : v2;  i2 = g2 ? (g1 ? i1 : (id)) : i2; \
    v1 = g1 ? (g0 ? v0 : (v)) : v1;  i1 = g1 ? (g0 ? i0 : (id)) : i1; \
    v0 = g0 ? (v) : v0;              i0 = g0 ? (id) : i0; \
}

// ---------------- inverse map ----------------
__global__ __launch_bounds__(256) void k_init_inv(int* __restrict__ inv) {
    int i = blockIdx.x*256 + threadIdx.x;
    inv[i] = -1;
}

__global__ __launch_bounds__(256) void k_scatter_inv(const int* __restrict__ coords,
                                                     int* __restrict__ inv) {
    int i = blockIdx.x*256 + threadIdx.x;
    if (i >= BB*PB) return;
    int b = i / PB, p = i % PB;
    const int* c = coords + (size_t)i*3;
    int flat = c[0] + c[1]*NXg + c[2];
    inv[b*SCELLS + flat] = p;
}

// ---------------- score + top-4: k_logits-pattern, 2 pillars/thread ----------------
// r9 analysis: r7 version was LDS-return-path-bound (4096 broadcast b128/wave
// x ~8cyc fan-out x 12 waves/CU ~ 164us; measured 180, VALU 84%). Each read
// fed only 4 FMAs (one pillar). This version: thread owns TWO pillar rows
// (wreg 32 f4); same point reads now feed 8 FMAs -> LDS traffic per CU
// halves (waves halve, reads/wave constant). Addressing stays broadcast +
// immediate-offset (the proven no-spill shape; r3 precedent: 152 VGPR clean).
// Spill tripwire: FETCH >> 16MB => revert to 1 pillar/thread.
__global__ __launch_bounds__(256) void k_score_topk(const float* __restrict__ pillars,
                                                    const float* __restrict__ points,
                                                    float* __restrict__ pV,
                                                    int* __restrict__ pI) {
    __shared__ float4 sPt[CHROWS*16];     // 64 point rows, 16 KB
    const int b = blockIdx.y;
    const int seg = blockIdx.z;
    const int t = threadIdx.x;
    const int pA = blockIdx.x*512 + t;          // always < PB (max 5887)
    const int pB = pA + 256;
    const int prB = pB < PB ? pB : PB-1;
    const int j0 = seg * SEGPTS;

    const float4* pil4  = (const float4*)pillars;
    const float4* ptsB4 = (const float4*)(points + (size_t)b*NPTS*DD);

    float4 wA[16], wB[16];
    #pragma unroll
    for (int d4 = 0; d4 < 16; d4++)
        wA[d4] = pil4[((size_t)b*PB + pA)*16 + d4];
    #pragma unroll
    for (int d4 = 0; d4 < 16; d4++)
        wB[d4] = pil4[((size_t)b*PB + prB)*16 + d4];

    float tvA0=NEG_INF, tvA1=NEG_INF, tvA2=NEG_INF, tvA3=NEG_INF;
    int   tiA0=0, tiA1=0, tiA2=0, tiA3=0;
    float tvB0=NEG_INF, tvB1=NEG_INF, tvB2=NEG_INF, tvB3=NEG_INF;
    int   tiB0=0, tiB1=0, tiB2=0, tiB3=0;

    for (int ch = 0; ch < NCHNK; ch++) {
        const float4* src = ptsB4 + (size_t)(j0 + ch*CHROWS)*16;
        for (int i = t; i < CHROWS*16; i += 256)
            sPt[i] = src[i];
        __syncthreads();

        const int jb = j0 + ch*CHROWS;
        for (int j = 0; j < CHROWS; j += 2) {
            float a0 = 0.f, a1 = 0.f, b0 = 0.f, b1 = 0.f;
            #pragma unroll
            for (int d4 = 0; d4 < 16; d4++) {
                float4 x0 = sPt[j*16 + d4];
                float4 x1 = sPt[(j+1)*16 + d4];
                a0 += wA[d4].x*x0.x + wA[d4].y*x0.y + wA[d4].z*x0.z + wA[d4].w*x0.w;
                a1 += wA[d4].x*x1.x + wA[d4].y*x1.y + wA[d4].z*x1.z + wA[d4].w*x1.w;
                b0 += wB[d4].x*x0.x + wB[d4].y*x0.y + wB[d4].z*x0.z + wB[d4].w*x0.w;
                b1 += wB[d4].x*x1.x + wB[d4].y*x1.y + wB[d4].z*x1.z + wB[d4].w*x1.w;
            }
            if (a0 > tvA3) INS4(a0, jb+j,   tvA0,tvA1,tvA2,tvA3, tiA0,tiA1,tiA2,tiA3)
            if (a1 > tvA3) INS4(a1, jb+j+1, tvA0,tvA1,tvA2,tvA3, tiA0,tiA1,tiA2,tiA3)
            if (b0 > tvB3) INS4(b0, jb+j,   tvB0,tvB1,tvB2,tvB3, tiB0,tiB1,tiB2,tiB3)
            if (b1 > tvB3) INS4(b1, jb+j+1, tvB0,tvB1,tvB2,tvB3, tiB0,tiB1,tiB2,tiB3)
        }
        __syncthreads();
    }

    {
        size_t ob = (((size_t)b*NSEG + seg)*PB + pA)*KK;
        pV[ob+0]=tvA0; pV[ob+1]=tvA1; pV[ob+2]=tvA2; pV[ob+3]=tvA3;
        pI[ob+0]=tiA0; pI[ob+1]=tiA1; pI[ob+2]=tiA2; pI[ob+3]=tiA3;
    }
    if (pB < PB) {
        size_t ob = (((size_t)b*NSEG + seg)*PB + pB)*KK;
        pV[ob+0]=tvB0; pV[ob+1]=tvB1; pV[ob+2]=tvB2; pV[ob+3]=tvB3;
        pI[ob+0]=tiB0; pI[ob+1]=tiB1; pI[ob+2]=tiB2; pI[ob+3]=tiB3;
    }
}

// ---------------- merge NSEG partial top-4 lists ----------------
__global__ __launch_bounds__(256) void k_merge(const float* __restrict__ pV,
                                               const int* __restrict__ pI,
                                               int* __restrict__ idxOut) {
    int i = blockIdx.x*256 + threadIdx.x;
    if (i >= BB*PB) return;
    int b = i / PB, p = i % PB;
    float fv0=NEG_INF, fv1=NEG_INF, fv2=NEG_INF, fv3=NEG_INF;
    int fi0=0, fi1=0, fi2=0, fi3=0;
    for (int s = 0; s < NSEG; s++) {   // ascending seg = ascending point ranges
        size_t base = (((size_t)b*NSEG + s)*PB + p)*KK;
        #pragma unroll
        for (int q = 0; q < 4; q++) {
            float v = pV[base+q];
            if (v > fv3) INS4(v, pI[base+q], fv0,fv1,fv2,fv3, fi0,fi1,fi2,fi3)
        }
    }
    idxOut[(size_t)i*KK+0]=fi0; idxOut[(size_t)i*KK+1]=fi1;
    idxOut[(size_t)i*KK+2]=fi2; idxOut[(size_t)i*KK+3]=fi3;
}

// ---------------- logits GEMM: X[24000x64] @ memw^T[64x1024] ----------------
__global__ __launch_bounds__(256) void k_logits(const float* __restrict__ points,
                                                const int* __restrict__ idxIn,
                                                const float* __restrict__ memw,
                                                float* __restrict__ logits,
                                                int b) {
    __shared__ float4 sX4[64*16];
    __shared__ int sId[64];
    const int t = threadIdx.x;
    const int lane = t & 63, wv = t >> 6;
    const int row0 = blockIdx.x * 64;
    const int cg = blockIdx.y * 256 + wv * 64;

    if (t < 64) sId[t] = idxIn[(size_t)b*NROWS + row0 + t];

    const float4* mw4 = (const float4*)memw;
    float4 wreg[16];
    #pragma unroll
    for (int d4 = 0; d4 < 16; d4++) wreg[d4] = mw4[(size_t)(cg + lane)*16 + d4];

    __syncthreads();
    const float4* ptsB4 = (const float4*)(points + (size_t)b*NPTS*DD);
    for (int i = t; i < 1024; i += 256) {
        int r = i >> 4, c = i & 15;
        sX4[i] = ptsB4[(size_t)sId[r]*16 + c];
    }
    __syncthreads();

    for (int r = 0; r < 64; r += 2) {
        float a0 = 0.f, a1 = 0.f;
        #pragma unroll
        for (int d4 = 0; d4 < 16; d4++) {
            float4 x0 = sX4[r*16 + d4];
            float4 x1 = sX4[(r+1)*16 + d4];
            a0 += wreg[d4].x*x0.x + wreg[d4].y*x0.y + wreg[d4].z*x0.z + wreg[d4].w*x0.w;
            a1 += wreg[d4].x*x1.x + wreg[d4].y*x1.y + wreg[d4].z*x1.z + wreg[d4].w*x1.w;
        }
        logits[(size_t)(row0 + r)*MM + cg + lane] = a0;
        logits[(size_t)(row0 + r + 1)*MM + cg + lane] = a1;
    }
}

// ---------------- mem-unit GEMM: stats + att-on-the-fly, writes mem_out ----------------
// r9: grid was 500 blocks = 2/CU (grid-limited, not resource-limited).
// Halve block work: 6 pillars (24 rows), acc[6], LDS 22.5KB -> grid 1000,
// ~4 blocks/CU, better exp/barrier overlap. Same proven instruction stream.
__global__ __launch_bounds__(256) void k_moG(const float* __restrict__ logits,
                                             const float* __restrict__ memw,
                                             float* __restrict__ mo,
                                             int b) {
    __shared__ __align__(16) char smem[22528];
    float4* sAtt4 = (float4*)smem;              // [24][16] f4 (6144 B)
    float4* sW4   = (float4*)(smem + 6144);     // [64 m][16 c4] (16384 B)
    float*  sWf   = (float*)sW4;
    __shared__ float sM[24], sRinv[24], sRsc[24];
    const int t = threadIdx.x;
    const int lane = t & 63, wv = t >> 6;
    const int p0 = blockIdx.x * MOP;
    const int row0 = p0 * 4;

    const float4* lg4 = (const float4*)logits;
    #pragma unroll
    for (int rr = 0; rr < MOP; rr++) {
        int r = wv*MOP + rr;
        size_t base = (size_t)(row0 + r)*256;
        float4 l0 = lg4[base + lane];
        float4 l1 = lg4[base + 64 + lane];
        float4 l2 = lg4[base + 128 + lane];
        float4 l3 = lg4[base + 192 + lane];
        float m = fmaxf(fmaxf(fmaxf(l0.x,l0.y),fmaxf(l0.z,l0.w)),
                 fmaxf(fmaxf(fmaxf(l1.x,l1.y),fmaxf(l1.z,l1.w)),
                 fmaxf(fmaxf(fmaxf(l2.x,l2.y),fmaxf(l2.z,l2.w)),
                       fmaxf(fmaxf(l3.x,l3.y),fmaxf(l3.z,l3.w)))));
        #pragma unroll
        for (int off = 1; off < 64; off <<= 1) m = fmaxf(m, __shfl_xor(m, off));
        l0.x=__expf(l0.x-m); l0.y=__expf(l0.y-m); l0.z=__expf(l0.z-m); l0.w=__expf(l0.w-m);
        l1.x=__expf(l1.x-m); l1.y=__expf(l1.y-m); l1.z=__expf(l1.z-m); l1.w=__expf(l1.w-m);
        l2.x=__expf(l2.x-m); l2.y=__expf(l2.y-m); l2.z=__expf(l2.z-m); l2.w=__expf(l2.w-m);
        l3.x=__expf(l3.x-m); l3.y=__expf(l3.y-m); l3.z=__expf(l3.z-m); l3.w=__expf(l3.w-m);
        float s = (l0.x+l0.y+l0.z+l0.w) + (l1.x+l1.y+l1.z+l1.w)
                + (l2.x+l2.y+l2.z+l2.w) + (l3.x+l3.y+l3.z+l3.w);
        #pragma unroll
        for (int off = 1; off < 64; off <<= 1) s += __shfl_xor(s, off);
        float rinv = 1.f / s;
        float sh = 0.f;
        {
            float e, tt;
            e=l0.x*rinv; tt=e-SHRINK_TH; sh += tt>0.f ? e*tt/(tt+1e-12f) : 0.f;
            e=l0.y*rinv; tt=e-SHRINK_TH; sh += tt>0.f ? e*tt/(tt+1e-12f) : 0.f;
            e=l0.z*rinv; tt=e-SHRINK_TH; sh += tt>0.f ? e*tt/(tt+1e-12f) : 0.f;
            e=l0.w*rinv; tt=e-SHRINK_TH; sh += tt>0.f ? e*tt/(tt+1e-12f) : 0.f;
            e=l1.x*rinv; tt=e-SHRINK_TH; sh += tt>0.f ? e*tt/(tt+1e-12f) : 0.f;
            e=l1.y*rinv; tt=e-SHRINK_TH; sh += tt>0.f ? e*tt/(tt+1e-12f) : 0.f;
            e=l1.z*rinv; tt=e-SHRINK_TH; sh += tt>0.f ? e*tt/(tt+1e-12f) : 0.f;
            e=l1.w*rinv; tt=e-SHRINK_TH; sh += tt>0.f ? e*tt/(tt+1e-12f) : 0.f;
            e=l2.x*rinv; tt=e-SHRINK_TH; sh += tt>0.f ? e*tt/(tt+1e-12f) : 0.f;
            e=l2.y*rinv; tt=e-SHRINK_TH; sh += tt>0.f ? e*tt/(tt+1e-12f) : 0.f;
            e=l2.z*rinv; tt=e-SHRINK_TH; sh += tt>0.f ? e*tt/(tt+1e-12f) : 0.f;
            e=l2.w*rinv; tt=e-SHRINK_TH; sh += tt>0.f ? e*tt/(tt+1e-12f) : 0.f;
            e=l3.x*rinv; tt=e-SHRINK_TH; sh += tt>0.f ? e*tt/(tt+1e-12f) : 0.f;
            e=l3.y*rinv; tt=e-SHRINK_TH; sh += tt>0.f ? e*tt/(tt+1e-12f) : 0.f;
            e=l3.z*rinv; tt=e-SHRINK_TH; sh += tt>0.f ? e*tt/(tt+1e-12f) : 0.f;
            e=l3.w*rinv; tt=e-SHRINK_TH; sh += tt>0.f ? e*tt/(tt+1e-12f) : 0.f;
        }
        #pragma unroll
        for (int off = 1; off < 64; off <<= 1) sh += __shfl_xor(sh, off);
        if (lane == 0) { sM[r] = m; sRinv[r] = rinv; sRsc[r] = 1.f/(sh + 1e-12f); }
    }
    __syncthreads();

    float acc[MOP];
    #pragma unroll
    for (int s=0;s<MOP;s++) acc[s]=0.f;
    const float4* mw4 = (const float4*)memw;

    for (int tile = 0; tile < 16; tile++) {
        __syncthreads();
        for (int i = t; i < 24*16; i += 256) {
            int rr = i >> 4, m4 = i & 15;
            float4 lg = lg4[(size_t)(row0 + rr)*256 + tile*16 + m4];
            float m = sM[rr], rinv = sRinv[rr], rsc = sRsc[rr];
            float4 o;
            float e, tt;
            e=__expf(lg.x-m)*rinv; tt=e-SHRINK_TH; o.x = (tt>0.f ? e*tt/(tt+1e-12f) : 0.f)*rsc;
            e=__expf(lg.y-m)*rinv; tt=e-SHRINK_TH; o.y = (tt>0.f ? e*tt/(tt+1e-12f) : 0.f)*rsc;
            e=__expf(lg.z-m)*rinv; tt=e-SHRINK_TH; o.z = (tt>0.f ? e*tt/(tt+1e-12f) : 0.f)*rsc;
            e=__expf(lg.w-m)*rinv; tt=e-SHRINK_TH; o.w = (tt>0.f ? e*tt/(tt+1e-12f) : 0.f)*rsc;
            sAtt4[rr*16 + m4] = o;
        }
        #pragma unroll 4
        for (int i = t; i < 1024; i += 256) {
            int m = i >> 4, c4 = i & 15;
            sW4[m*16 + c4] = mw4[(size_t)(tile*64 + m)*16 + c4];
        }
        __syncthreads();
        #pragma unroll 4
        for (int m4 = 0; m4 < 16; m4++) {
            float w0 = sWf[(m4*4+0)*64 + lane];
            float w1 = sWf[(m4*4+1)*64 + lane];
            float w2 = sWf[(m4*4+2)*64 + lane];
            float w3 = sWf[(m4*4+3)*64 + lane];
            #pragma unroll
            for (int s = 0; s < MOP; s++) {
                float4 a4 = sAtt4[(wv + 4*s)*16 + m4];
                acc[s] += a4.x*w0 + a4.y*w1 + a4.z*w2 + a4.w*w3;
            }
        }
    }
    // write mem_out: local row r = wv+4s -> pillar p0+(r>>2), k-quarter r&3
    #pragma unroll
    for (int s = 0; s < MOP; s++) {
        int r = wv + 4*s;
        mo[(size_t)(p0 + (r >> 2))*256 + (r & 3)*64 + lane] = acc[s];
    }
}

// ---------------- adapt: h = mem_out @ adaptw^T ----------------
__global__ __launch_bounds__(256) void k_adapt(const float* __restrict__ mo,
                                               const float* __restrict__ adaptw,
                                               float* __restrict__ hOut,
                                               int b) {
    __shared__ __align__(16) char smem[77824];
    float* sMo = (float*)smem;                  // [48][64] = 12 pillar rows x 256
    float4* sA4 = (float4*)(smem + 12288);      // adaptw swizzled (64 KB)
    const int t = threadIdx.x;
    const int lane = t & 63, wv = t >> 6;
    const int p0 = blockIdx.x * 12;

    const float4* mo4 = (const float4*)(mo + (size_t)p0*256);
    float4* sMo4w = (float4*)sMo;
    #pragma unroll
    for (int q = 0; q < 3; q++)
        sMo4w[q*256 + t] = mo4[q*256 + t];
    const float4* adG4 = (const float4*)adaptw;
    for (int i = t; i < 4096; i += 256) {
        int c = i >> 6, j4 = i & 63;
        sA4[c*64 + (j4 ^ (c & 15))] = adG4[c*64 + j4];
    }
    __syncthreads();
    const float4* sMo4 = (const float4*)sMo;
    float h0=0.f, h1=0.f, h2=0.f;
    #pragma unroll 8
    for (int j4 = 0; j4 < 64; j4++) {
        float4 a4 = sA4[lane*64 + (j4 ^ (lane & 15))];
        int sub = (j4 >> 4)*16 + (j4 & 15);
        float4 q0 = sMo4[(4*(wv+0))*16 + sub];
        float4 q1 = sMo4[(4*(wv+4))*16 + sub];
        float4 q2 = sMo4[(4*(wv+8))*16 + sub];
        h0 += q0.x*a4.x + q0.y*a4.y + q0.z*a4.z + q0.w*a4.w;
        h1 += q1.x*a4.x + q1.y*a4.y + q1.z*a4.z + q1.w*a4.w;
        h2 += q2.x*a4.x + q2.y*a4.y + q2.z*a4.z + q2.w*a4.w;
    }
    hOut[((size_t)b*PB + p0 + wv + 0)*DD + lane] = h0;
    hOut[((size_t)b*PB + p0 + wv + 4)*DD + lane] = h1;
    hOut[((size_t)b*PB + p0 + wv + 8)*DD + lane] = h2;
}

// ---------------- batchnorm stats, two-stage ----------------
__global__ __launch_bounds__(256) void k_bn1(const float* __restrict__ h,
                                             float* __restrict__ pSum,
                                             float* __restrict__ pSq) {
    const int bid = blockIdx.x;
    const int b = bid >> 5, ch = bid & 31;
    const int r0 = ch*188;
    int r1 = r0 + 188; if (r1 > PB) r1 = PB;
    __shared__ float sS[4*64], sS2[4*64];
    const int t = threadIdx.x;
    const int c = t & 63, stripe = t >> 6;
    float s = 0.f, s2 = 0.f;
    for (int r = r0 + stripe; r < r1; r += 4) {
        float v = h[((size_t)b*PB + r)*DD + c];
        s += v; s2 += v*v;
    }
    sS[stripe*64 + c] = s; sS2[stripe*64 + c] = s2;
    __syncthreads();
    if (t < 64) {
        float ts = sS[t] + sS[64+t] + sS[128+t] + sS[192+t];
        float ts2 = sS2[t] + sS2[64+t] + sS2[128+t] + sS2[192+t];
        pSum[(size_t)bid*64 + t] = ts;
        pSq[(size_t)bid*64 + t] = ts2;
    }
}

__global__ __launch_bounds__(64) void k_bn2(const float* __restrict__ pSum,
                                            const float* __restrict__ pSq,
                                            const float* __restrict__ gamma,
                                            float* __restrict__ bnMu,
                                            float* __restrict__ bnScale) {
    const int b = blockIdx.x;
    const int t = threadIdx.x;
    float ts = 0.f, ts2 = 0.f;
    for (int ch = 0; ch < 32; ch++) {
        ts += pSum[(size_t)(b*32 + ch)*64 + t];
        ts2 += pSq[(size_t)(b*32 + ch)*64 + t];
    }
    float mu = ts / (float)PB;
    float var = ts2 / (float)PB - mu*mu;
    if (var < 0.f) var = 0.f;
    bnMu[b*64+t] = mu;
    bnScale[b*64+t] = gamma[t] / sqrtf(var + BN_EPS);
}

// ---------------- dense fill (gather) ----------------
__global__ __launch_bounds__(256) void k_fill(const int* __restrict__ inv,
                                              const float* __restrict__ pillars,
                                              const float* __restrict__ h,
                                              const float* __restrict__ bnMu,
                                              const float* __restrict__ bnScale,
                                              const float* __restrict__ beta,
                                              float* __restrict__ out) {
    const int b = blockIdx.y;
    const int f = blockIdx.x*256 + threadIdx.x;
    __shared__ float sMu[64], sSc[64], sBe[64];
    if (threadIdx.x < 64) {
        sMu[threadIdx.x] = bnMu[b*64+threadIdx.x];
        sSc[threadIdx.x] = bnScale[b*64+threadIdx.x];
        sBe[threadIdx.x] = beta[threadIdx.x];
    }
    __syncthreads();
    int iv = inv[b*SCELLS + f];
    bool occ = iv >= 0;
    int iv0 = occ ? iv : 0;
    float* sp = out + (size_t)b*128*SCELLS;
    const float* prow = pillars + ((size_t)b*PB + iv0)*DD;
    const float* hrow = h + ((size_t)b*PB + iv0)*DD;
    #pragma unroll 4
    for (int c = 0; c < 64; c++)
        sp[(size_t)c*SCELLS + f] = occ ? prow[c] : 0.f;
    #pragma unroll 4
    for (int c = 0; c < 64; c++) {
        float v = 0.f;
        if (occ) {
            float hv = hrow[c];
            v = fmaxf((hv - sMu[c])*sSc[c] + sBe[c], 0.f);
        }
        sp[(size_t)(64+c)*SCELLS + f] = v;
    }
    float* pi = out + (size_t)BB*128*SCELLS + (size_t)b*3*SCELLS;
    pi[f]              = occ ? (float)(f / NXg) : 0.f;
    pi[SCELLS + f]     = occ ? (float)(f % NXg) : 0.f;
    pi[2*(size_t)SCELLS + f] = 0.f;
}

extern "C" void kernel_launch(void* const* d_in, const int* in_sizes, int n_in,
                              void* d_out, int out_size, void* d_ws, size_t ws_size,
                              hipStream_t stream) {
    const float* pillars = (const float*)d_in[0];
    const float* points  = (const float*)d_in[1];
    const int*   coords  = (const int*)d_in[2];
    const float* adaptw  = (const float*)d_in[3];
    const float* memw    = (const float*)d_in[4];
    const float* gamma   = (const float*)d_in[5];
    const float* beta    = (const float*)d_in[6];
    float* out = (float*)d_out;

    char* w = (char*)d_ws;
    int* inv = (int*)w;        w += (size_t)BB*SCELLS*4;
    int* idx = (int*)w;        w += (size_t)BB*PB*KK*4;
    float* h = (float*)w;      w += (size_t)BB*PB*DD*4;
    float* bnMu = (float*)w;   w += (size_t)BB*64*4;
    float* bnScale = (float*)w; w += (size_t)BB*64*4;
    float* pSum = (float*)w;   w += (size_t)BB*32*64*4;
    float* pSq = (float*)w;    w += (size_t)BB*32*64*4;
    float* mo = (float*)w;     w += (size_t)PB*256*4;       // 6.1 MB, per-batch reuse
    float* logits = (float*)w;                    // 98.3 MB, per-batch reuse
    // pV/pI alias logits: score+merge fully complete (stream-ordered) before
    // k_logits writes this region. 2*16*6000*4*4B*2 = 6.1 MB << 98.3 MB.
    float* pV = logits;
    int*   pI = (int*)(logits + (size_t)BB*NSEG*PB*KK);

    k_init_inv<<<dim3(BB*SCELLS/256), dim3(256), 0, stream>>>(inv);
    k_scatter_inv<<<dim3((BB*PB+255)/256), dim3(256), 0, stream>>>(coords, inv);
    k_score_topk<<<dim3((PB+511)/512, BB, NSEG), dim3(256), 0, stream>>>(pillars, points, pV, pI);
    k_merge<<<dim3((BB*PB+255)/256), dim3(256), 0, stream>>>(pV, pI, idx);
    for (int b = 0; b < BB; b++) {
        k_logits<<<dim3(NROWS/64, 4), dim3(256), 0, stream>>>(points, idx, memw, logits, b);
        k_moG<<<dim3(PB/MOP), dim3(256), 0, stream>>>(logits, memw, mo, b);
        k_adapt<<<dim3(PB/12), dim3(256), 0, stream>>>(mo, adaptw, h, b);
    }
    k_bn1<<<dim3(BB*32), dim3(256), 0, stream>>>(h, pSum, pSq);
    k_bn2<<<dim3(BB), dim3(64), 0, stream>>>(pSum, pSq, gamma, bnMu, bnScale);
    k_fill<<<dim3(SCELLS/256, BB), dim3(256), 0, stream>>>(inv, pillars, h, bnMu, bnScale, beta, out);
}

// Round 11
// 875.636 us; speedup vs baseline: 1.0425x; 1.0425x over previous
//
#include <hip/hip_runtime.h>

#define NXg 432
#define NYg 496
#define SCELLS (NXg*NYg)   // 214272
#define PB 6000
#define NPTS 4096
#define DD 64
#define MM 1024
#define KK 4
#define BB 2
#define NROWS (PB*KK)      // 24000
#define NSEG 32
#define SEGPTS (NPTS/NSEG) // 128 points per segment
#define CHROWS 64          // point rows staged per LDS chunk
#define NCHNK (SEGPTS/CHROWS) // 2 chunks
#define MOP 6              // pillars per k_moG block
#define SHRINK_TH 0.0025f
#define BN_EPS 1e-3f
#define NEG_INF -3.402823466e38f

// sorted-descending top-4 insert on NAMED scalars; caller guarantees v > v3.
// Scans are ascending-index, so strict > keeps earliest index on ties.
#define INS4(v, id, v0,v1,v2,v3, i0,i1,i2,i3) { \
    bool g0 = (v) > v0, g1 = (v) > v1, g2 = (v) > v2; \
    v3 = g2 ? v2 : (v);              i3 = g2 ? i2 : (id); \
    v2 = g2 ? (g1 ? v1 : (v)) : v2;  i2 = g2 ? (g1 ? i1 : (id)) : i2; \
    v1 = g1 ? (g0 ? v0 : (v)) : v1;  i1 = g1 ? (g0 ? i0 : (id)) : i1; \
    v0 = g0 ? (v) : v0;              i0 = g0 ? (id) : i0; \
}

// ---------------- inverse map ----------------
__global__ __launch_bounds__(256) void k_init_inv(int* __restrict__ inv) {
    int i = blockIdx.x*256 + threadIdx.x;
    inv[i] = -1;
}

__global__ __launch_bounds__(256) void k_scatter_inv(const int* __restrict__ coords,
                                                     int* __restrict__ inv) {
    int i = blockIdx.x*256 + threadIdx.x;
    if (i >= BB*PB) return;
    int b = i / PB, p = i % PB;
    const int* c = coords + (size_t)i*3;
    int flat = c[0] + c[1]*NXg + c[2];
    inv[b*SCELLS + flat] = p;
}

// ---------------- score + top-4: 2 pillars/thread, NSEG=32 ----------------
// r10 post-mortem: the 2-pillar rewrite was register-clean (VGPR 148, FETCH
// 9.7MB, no spill) but I halved blockIdx.x without compensating: grid 384
// blocks = 1.5 blocks/CU (occupancy 8.9%) -> latency-exposed at 47% VALU.
// Fix: NSEG 16->32 (segment 128 pts = 2 chunks) restores grid to 768 blocks
// = 3 blocks/CU = 12 waves/CU (r7's occupancy) while keeping the halved
// per-CU LDS traffic: 3072 waves x 2048 broadcast-b128 x ~8cyc / 256 CU
// ~ 82us LDS-bound (FMA floor 40us). Addressing stays broadcast +
// immediate-offset (no-spill shape).
__global__ __launch_bounds__(256) void k_score_topk(const float* __restrict__ pillars,
                                                    const float* __restrict__ points,
                                                    float* __restrict__ pV,
                                                    int* __restrict__ pI) {
    __shared__ float4 sPt[CHROWS*16];     // 64 point rows, 16 KB
    const int b = blockIdx.y;
    const int seg = blockIdx.z;
    const int t = threadIdx.x;
    const int pA = blockIdx.x*512 + t;          // always < PB (max 5887)
    const int pB = pA + 256;
    const int prB = pB < PB ? pB : PB-1;
    const int j0 = seg * SEGPTS;

    const float4* pil4  = (const float4*)pillars;
    const float4* ptsB4 = (const float4*)(points + (size_t)b*NPTS*DD);

    float4 wA[16], wB[16];
    #pragma unroll
    for (int d4 = 0; d4 < 16; d4++)
        wA[d4] = pil4[((size_t)b*PB + pA)*16 + d4];
    #pragma unroll
    for (int d4 = 0; d4 < 16; d4++)
        wB[d4] = pil4[((size_t)b*PB + prB)*16 + d4];

    float tvA0=NEG_INF, tvA1=NEG_INF, tvA2=NEG_INF, tvA3=NEG_INF;
    int   tiA0=0, tiA1=0, tiA2=0, tiA3=0;
    float tvB0=NEG_INF, tvB1=NEG_INF, tvB2=NEG_INF, tvB3=NEG_INF;
    int   tiB0=0, tiB1=0, tiB2=0, tiB3=0;

    for (int ch = 0; ch < NCHNK; ch++) {
        const float4* src = ptsB4 + (size_t)(j0 + ch*CHROWS)*16;
        for (int i = t; i < CHROWS*16; i += 256)
            sPt[i] = src[i];
        __syncthreads();

        const int jb = j0 + ch*CHROWS;
        for (int j = 0; j < CHROWS; j += 2) {
            float a0 = 0.f, a1 = 0.f, b0 = 0.f, b1 = 0.f;
            #pragma unroll
            for (int d4 = 0; d4 < 16; d4++) {
                float4 x0 = sPt[j*16 + d4];
                float4 x1 = sPt[(j+1)*16 + d4];
                a0 += wA[d4].x*x0.x + wA[d4].y*x0.y + wA[d4].z*x0.z + wA[d4].w*x0.w;
                a1 += wA[d4].x*x1.x + wA[d4].y*x1.y + wA[d4].z*x1.z + wA[d4].w*x1.w;
                b0 += wB[d4].x*x0.x + wB[d4].y*x0.y + wB[d4].z*x0.z + wB[d4].w*x0.w;
                b1 += wB[d4].x*x1.x + wB[d4].y*x1.y + wB[d4].z*x1.z + wB[d4].w*x1.w;
            }
            if (a0 > tvA3) INS4(a0, jb+j,   tvA0,tvA1,tvA2,tvA3, tiA0,tiA1,tiA2,tiA3)
            if (a1 > tvA3) INS4(a1, jb+j+1, tvA0,tvA1,tvA2,tvA3, tiA0,tiA1,tiA2,tiA3)
            if (b0 > tvB3) INS4(b0, jb+j,   tvB0,tvB1,tvB2,tvB3, tiB0,tiB1,tiB2,tiB3)
            if (b1 > tvB3) INS4(b1, jb+j+1, tvB0,tvB1,tvB2,tvB3, tiB0,tiB1,tiB2,tiB3)
        }
        __syncthreads();
    }

    {
        size_t ob = (((size_t)b*NSEG + seg)*PB + pA)*KK;
        pV[ob+0]=tvA0; pV[ob+1]=tvA1; pV[ob+2]=tvA2; pV[ob+3]=tvA3;
        pI[ob+0]=tiA0; pI[ob+1]=tiA1; pI[ob+2]=tiA2; pI[ob+3]=tiA3;
    }
    if (pB < PB) {
        size_t ob = (((size_t)b*NSEG + seg)*PB + pB)*KK;
        pV[ob+0]=tvB0; pV[ob+1]=tvB1; pV[ob+2]=tvB2; pV[ob+3]=tvB3;
        pI[ob+0]=tiB0; pI[ob+1]=tiB1; pI[ob+2]=tiB2; pI[ob+3]=tiB3;
    }
}

// ---------------- merge NSEG partial top-4 lists ----------------
__global__ __launch_bounds__(256) void k_merge(const float* __restrict__ pV,
                                               const int* __restrict__ pI,
                                               int* __restrict__ idxOut) {
    int i = blockIdx.x*256 + threadIdx.x;
    if (i >= BB*PB) return;
    int b = i / PB, p = i % PB;
    float fv0=NEG_INF, fv1=NEG_INF, fv2=NEG_INF, fv3=NEG_INF;
    int fi0=0, fi1=0, fi2=0, fi3=0;
    for (int s = 0; s < NSEG; s++) {   // ascending seg = ascending point ranges
        size_t base = (((size_t)b*NSEG + s)*PB + p)*KK;
        #pragma unroll
        for (int q = 0; q < 4; q++) {
            float v = pV[base+q];
            if (v > fv3) INS4(v, pI[base+q], fv0,fv1,fv2,fv3, fi0,fi1,fi2,fi3)
        }
    }
    idxOut[(size_t)i*KK+0]=fi0; idxOut[(size_t)i*KK+1]=fi1;
    idxOut[(size_t)i*KK+2]=fi2; idxOut[(size_t)i*KK+3]=fi3;
}

// ---------------- logits GEMM: X[24000x64] @ memw^T[64x1024] ----------------
__global__ __launch_bounds__(256) void k_logits(const float* __restrict__ points,
                                                const int* __restrict__ idxIn,
                                                const float* __restrict__ memw,
                                                float* __restrict__ logits,
                                                int b) {
    __shared__ float4 sX4[64*16];
    __shared__ int sId[64];
    const int t = threadIdx.x;
    const int lane = t & 63, wv = t >> 6;
    const int row0 = blockIdx.x * 64;
    const int cg = blockIdx.y * 256 + wv * 64;

    if (t < 64) sId[t] = idxIn[(size_t)b*NROWS + row0 + t];

    const float4* mw4 = (const float4*)memw;
    float4 wreg[16];
    #pragma unroll
    for (int d4 = 0; d4 < 16; d4++) wreg[d4] = mw4[(size_t)(cg + lane)*16 + d4];

    __syncthreads();
    const float4* ptsB4 = (const float4*)(points + (size_t)b*NPTS*DD);
    for (int i = t; i < 1024; i += 256) {
        int r = i >> 4, c = i & 15;
        sX4[i] = ptsB4[(size_t)sId[r]*16 + c];
    }
    __syncthreads();

    for (int r = 0; r < 64; r += 2) {
        float a0 = 0.f, a1 = 0.f;
        #pragma unroll
        for (int d4 = 0; d4 < 16; d4++) {
            float4 x0 = sX4[r*16 + d4];
            float4 x1 = sX4[(r+1)*16 + d4];
            a0 += wreg[d4].x*x0.x + wreg[d4].y*x0.y + wreg[d4].z*x0.z + wreg[d4].w*x0.w;
            a1 += wreg[d4].x*x1.x + wreg[d4].y*x1.y + wreg[d4].z*x1.z + wreg[d4].w*x1.w;
        }
        logits[(size_t)(row0 + r)*MM + cg + lane] = a0;
        logits[(size_t)(row0 + r + 1)*MM + cg + lane] = a1;
    }
}

// ---------------- mem-unit GEMM: stats + att-on-the-fly, writes mem_out ----------------
__global__ __launch_bounds__(256) void k_moG(const float* __restrict__ logits,
                                             const float* __restrict__ memw,
                                             float* __restrict__ mo,
                                             int b) {
    __shared__ __align__(16) char smem[22528];
    float4* sAtt4 = (float4*)smem;              // [24][16] f4 (6144 B)
    float4* sW4   = (float4*)(smem + 6144);     // [64 m][16 c4] (16384 B)
    float*  sWf   = (float*)sW4;
    __shared__ float sM[24], sRinv[24], sRsc[24];
    const int t = threadIdx.x;
    const int lane = t & 63, wv = t >> 6;
    const int p0 = blockIdx.x * MOP;
    const int row0 = p0 * 4;

    const float4* lg4 = (const float4*)logits;
    #pragma unroll
    for (int rr = 0; rr < MOP; rr++) {
        int r = wv*MOP + rr;
        size_t base = (size_t)(row0 + r)*256;
        float4 l0 = lg4[base + lane];
        float4 l1 = lg4[base + 64 + lane];
        float4 l2 = lg4[base + 128 + lane];
        float4 l3 = lg4[base + 192 + lane];
        float m = fmaxf(fmaxf(fmaxf(l0.x,l0.y),fmaxf(l0.z,l0.w)),
                 fmaxf(fmaxf(fmaxf(l1.x,l1.y),fmaxf(l1.z,l1.w)),
                 fmaxf(fmaxf(fmaxf(l2.x,l2.y),fmaxf(l2.z,l2.w)),
                       fmaxf(fmaxf(l3.x,l3.y),fmaxf(l3.z,l3.w)))));
        #pragma unroll
        for (int off = 1; off < 64; off <<= 1) m = fmaxf(m, __shfl_xor(m, off));
        l0.x=__expf(l0.x-m); l0.y=__expf(l0.y-m); l0.z=__expf(l0.z-m); l0.w=__expf(l0.w-m);
        l1.x=__expf(l1.x-m); l1.y=__expf(l1.y-m); l1.z=__expf(l1.z-m); l1.w=__expf(l1.w-m);
        l2.x=__expf(l2.x-m); l2.y=__expf(l2.y-m); l2.z=__expf(l2.z-m); l2.w=__expf(l2.w-m);
        l3.x=__expf(l3.x-m); l3.y=__expf(l3.y-m); l3.z=__expf(l3.z-m); l3.w=__expf(l3.w-m);
        float s = (l0.x+l0.y+l0.z+l0.w) + (l1.x+l1.y+l1.z+l1.w)
                + (l2.x+l2.y+l2.z+l2.w) + (l3.x+l3.y+l3.z+l3.w);
        #pragma unroll
        for (int off = 1; off < 64; off <<= 1) s += __shfl_xor(s, off);
        float rinv = 1.f / s;
        float sh = 0.f;
        {
            float e, tt;
            e=l0.x*rinv; tt=e-SHRINK_TH; sh += tt>0.f ? e*tt/(tt+1e-12f) : 0.f;
            e=l0.y*rinv; tt=e-SHRINK_TH; sh += tt>0.f ? e*tt/(tt+1e-12f) : 0.f;
            e=l0.z*rinv; tt=e-SHRINK_TH; sh += tt>0.f ? e*tt/(tt+1e-12f) : 0.f;
            e=l0.w*rinv; tt=e-SHRINK_TH; sh += tt>0.f ? e*tt/(tt+1e-12f) : 0.f;
            e=l1.x*rinv; tt=e-SHRINK_TH; sh += tt>0.f ? e*tt/(tt+1e-12f) : 0.f;
            e=l1.y*rinv; tt=e-SHRINK_TH; sh += tt>0.f ? e*tt/(tt+1e-12f) : 0.f;
            e=l1.z*rinv; tt=e-SHRINK_TH; sh += tt>0.f ? e*tt/(tt+1e-12f) : 0.f;
            e=l1.w*rinv; tt=e-SHRINK_TH; sh += tt>0.f ? e*tt/(tt+1e-12f) : 0.f;
            e=l2.x*rinv; tt=e-SHRINK_TH; sh += tt>0.f ? e*tt/(tt+1e-12f) : 0.f;
            e=l2.y*rinv; tt=e-SHRINK_TH; sh += tt>0.f ? e*tt/(tt+1e-12f) : 0.f;
            e=l2.z*rinv; tt=e-SHRINK_TH; sh += tt>0.f ? e*tt/(tt+1e-12f) : 0.f;
            e=l2.w*rinv; tt=e-SHRINK_TH; sh += tt>0.f ? e*tt/(tt+1e-12f) : 0.f;
            e=l3.x*rinv; tt=e-SHRINK_TH; sh += tt>0.f ? e*tt/(tt+1e-12f) : 0.f;
            e=l3.y*rinv; tt=e-SHRINK_TH; sh += tt>0.f ? e*tt/(tt+1e-12f) : 0.f;
            e=l3.z*rinv; tt=e-SHRINK_TH; sh += tt>0.f ? e*tt/(tt+1e-12f) : 0.f;
            e=l3.w*rinv; tt=e-SHRINK_TH; sh += tt>0.f ? e*tt/(tt+1e-12f) : 0.f;
        }
        #pragma unroll
        for (int off = 1; off < 64; off <<= 1) sh += __shfl_xor(sh, off);
        if (lane == 0) { sM[r] = m; sRinv[r] = rinv; sRsc[r] = 1.f/(sh + 1e-12f); }
    }
    __syncthreads();

    float acc[MOP];
    #pragma unroll
    for (int s=0;s<MOP;s++) acc[s]=0.f;
    const float4* mw4 = (const float4*)memw;

    for (int tile = 0; tile < 16; tile++) {
        __syncthreads();
        for (int i = t; i < 24*16; i += 256) {
            int rr = i >> 4, m4 = i & 15;
            float4 lg = lg4[(size_t)(row0 + rr)*256 + tile*16 + m4];
            float m = sM[rr], rinv = sRinv[rr], rsc = sRsc[rr];
            float4 o;
            float e, tt;
            e=__expf(lg.x-m)*rinv; tt=e-SHRINK_TH; o.x = (tt>0.f ? e*tt/(tt+1e-12f) : 0.f)*rsc;
            e=__expf(lg.y-m)*rinv; tt=e-SHRINK_TH; o.y = (tt>0.f ? e*tt/(tt+1e-12f) : 0.f)*rsc;
            e=__expf(lg.z-m)*rinv; tt=e-SHRINK_TH; o.z = (tt>0.f ? e*tt/(tt+1e-12f) : 0.f)*rsc;
            e=__expf(lg.w-m)*rinv; tt=e-SHRINK_TH; o.w = (tt>0.f ? e*tt/(tt+1e-12f) : 0.f)*rsc;
            sAtt4[rr*16 + m4] = o;
        }
        #pragma unroll 4
        for (int i = t; i < 1024; i += 256) {
            int m = i >> 4, c4 = i & 15;
            sW4[m*16 + c4] = mw4[(size_t)(tile*64 + m)*16 + c4];
        }
        __syncthreads();
        #pragma unroll 4
        for (int m4 = 0; m4 < 16; m4++) {
            float w0 = sWf[(m4*4+0)*64 + lane];
            float w1 = sWf[(m4*4+1)*64 + lane];
            float w2 = sWf[(m4*4+2)*64 + lane];
            float w3 = sWf[(m4*4+3)*64 + lane];
            #pragma unroll
            for (int s = 0; s < MOP; s++) {
                float4 a4 = sAtt4[(wv + 4*s)*16 + m4];
                acc[s] += a4.x*w0 + a4.y*w1 + a4.z*w2 + a4.w*w3;
            }
        }
    }
    // write mem_out: local row r = wv+4s -> pillar p0+(r>>2), k-quarter r&3
    #pragma unroll
    for (int s = 0; s < MOP; s++) {
        int r = wv + 4*s;
        mo[(size_t)(p0 + (r >> 2))*256 + (r & 3)*64 + lane] = acc[s];
    }
}

// ---------------- adapt: h = mem_out @ adaptw^T ----------------
__global__ __launch_bounds__(256) void k_adapt(const float* __restrict__ mo,
                                               const float* __restrict__ adaptw,
                                               float* __restrict__ hOut,
                                               int b) {
    __shared__ __align__(16) char smem[77824];
    float* sMo = (float*)smem;                  // [48][64] = 12 pillar rows x 256
    float4* sA4 = (float4*)(smem + 12288);      // adaptw swizzled (64 KB)
    const int t = threadIdx.x;
    const int lane = t & 63, wv = t >> 6;
    const int p0 = blockIdx.x * 12;

    const float4* mo4 = (const float4*)(mo + (size_t)p0*256);
    float4* sMo4w = (float4*)sMo;
    #pragma unroll
    for (int q = 0; q < 3; q++)
        sMo4w[q*256 + t] = mo4[q*256 + t];
    const float4* adG4 = (const float4*)adaptw;
    for (int i = t; i < 4096; i += 256) {
        int c = i >> 6, j4 = i & 63;
        sA4[c*64 + (j4 ^ (c & 15))] = adG4[c*64 + j4];
    }
    __syncthreads();
    const float4* sMo4 = (const float4*)sMo;
    float h0=0.f, h1=0.f, h2=0.f;
    #pragma unroll 8
    for (int j4 = 0; j4 < 64; j4++) {
        float4 a4 = sA4[lane*64 + (j4 ^ (lane & 15))];
        int sub = (j4 >> 4)*16 + (j4 & 15);
        float4 q0 = sMo4[(4*(wv+0))*16 + sub];
        float4 q1 = sMo4[(4*(wv+4))*16 + sub];
        float4 q2 = sMo4[(4*(wv+8))*16 + sub];
        h0 += q0.x*a4.x + q0.y*a4.y + q0.z*a4.z + q0.w*a4.w;
        h1 += q1.x*a4.x + q1.y*a4.y + q1.z*a4.z + q1.w*a4.w;
        h2 += q2.x*a4.x + q2.y*a4.y + q2.z*a4.z + q2.w*a4.w;
    }
    hOut[((size_t)b*PB + p0 + wv + 0)*DD + lane] = h0;
    hOut[((size_t)b*PB + p0 + wv + 4)*DD + lane] = h1;
    hOut[((size_t)b*PB + p0 + wv + 8)*DD + lane] = h2;
}

// ---------------- batchnorm stats, two-stage ----------------
__global__ __launch_bounds__(256) void k_bn1(const float* __restrict__ h,
                                             float* __restrict__ pSum,
                                             float* __restrict__ pSq) {
    const int bid = blockIdx.x;
    const int b = bid >> 5, ch = bid & 31;
    const int r0 = ch*188;
    int r1 = r0 + 188; if (r1 > PB) r1 = PB;
    __shared__ float sS[4*64], sS2[4*64];
    const int t = threadIdx.x;
    const int c = t & 63, stripe = t >> 6;
    float s = 0.f, s2 = 0.f;
    for (int r = r0 + stripe; r < r1; r += 4) {
        float v = h[((size_t)b*PB + r)*DD + c];
        s += v; s2 += v*v;
    }
    sS[stripe*64 + c] = s; sS2[stripe*64 + c] = s2;
    __syncthreads();
    if (t < 64) {
        float ts = sS[t] + sS[64+t] + sS[128+t] + sS[192+t];
        float ts2 = sS2[t] + sS2[64+t] + sS2[128+t] + sS2[192+t];
        pSum[(size_t)bid*64 + t] = ts;
        pSq[(size_t)bid*64 + t] = ts2;
    }
}

__global__ __launch_bounds__(64) void k_bn2(const float* __restrict__ pSum,
                                            const float* __restrict__ pSq,
                                            const float* __restrict__ gamma,
                                            float* __restrict__ bnMu,
                                            float* __restrict__ bnScale) {
    const int b = blockIdx.x;
    const int t = threadIdx.x;
    float ts = 0.f, ts2 = 0.f;
    for (int ch = 0; ch < 32; ch++) {
        ts += pSum[(size_t)(b*32 + ch)*64 + t];
        ts2 += pSq[(size_t)(b*32 + ch)*64 + t];
    }
    float mu = ts / (float)PB;
    float var = ts2 / (float)PB - mu*mu;
    if (var < 0.f) var = 0.f;
    bnMu[b*64+t] = mu;
    bnScale[b*64+t] = gamma[t] / sqrtf(var + BN_EPS);
}

// ---------------- dense fill (gather) ----------------
__global__ __launch_bounds__(256) void k_fill(const int* __restrict__ inv,
                                              const float* __restrict__ pillars,
                                              const float* __restrict__ h,
                                              const float* __restrict__ bnMu,
                                              const float* __restrict__ bnScale,
                                              const float* __restrict__ beta,
                                              float* __restrict__ out) {
    const int b = blockIdx.y;
    const int f = blockIdx.x*256 + threadIdx.x;
    __shared__ float sMu[64], sSc[64], sBe[64];
    if (threadIdx.x < 64) {
        sMu[threadIdx.x] = bnMu[b*64+threadIdx.x];
        sSc[threadIdx.x] = bnScale[b*64+threadIdx.x];
        sBe[threadIdx.x] = beta[threadIdx.x];
    }
    __syncthreads();
    int iv = inv[b*SCELLS + f];
    bool occ = iv >= 0;
    int iv0 = occ ? iv : 0;
    float* sp = out + (size_t)b*128*SCELLS;
    const float* prow = pillars + ((size_t)b*PB + iv0)*DD;
    const float* hrow = h + ((size_t)b*PB + iv0)*DD;
    #pragma unroll 4
    for (int c = 0; c < 64; c++)
        sp[(size_t)c*SCELLS + f] = occ ? prow[c] : 0.f;
    #pragma unroll 4
    for (int c = 0; c < 64; c++) {
        float v = 0.f;
        if (occ) {
            float hv = hrow[c];
            v = fmaxf((hv - sMu[c])*sSc[c] + sBe[c], 0.f);
        }
        sp[(size_t)(64+c)*SCELLS + f] = v;
    }
    float* pi = out + (size_t)BB*128*SCELLS + (size_t)b*3*SCELLS;
    pi[f]              = occ ? (float)(f / NXg) : 0.f;
    pi[SCELLS + f]     = occ ? (float)(f % NXg) : 0.f;
    pi[2*(size_t)SCELLS + f] = 0.f;
}

extern "C" void kernel_launch(void* const* d_in, const int* in_sizes, int n_in,
                              void* d_out, int out_size, void* d_ws, size_t ws_size,
                              hipStream_t stream) {
    const float* pillars = (const float*)d_in[0];
    const float* points  = (const float*)d_in[1];
    const int*   coords  = (const int*)d_in[2];
    const float* adaptw  = (const float*)d_in[3];
    const float* memw    = (const float*)d_in[4];
    const float* gamma   = (const float*)d_in[5];
    const float* beta    = (const float*)d_in[6];
    float* out = (float*)d_out;

    char* w = (char*)d_ws;
    int* inv = (int*)w;        w += (size_t)BB*SCELLS*4;
    int* idx = (int*)w;        w += (size_t)BB*PB*KK*4;
    float* h = (float*)w;      w += (size_t)BB*PB*DD*4;
    float* bnMu = (float*)w;   w += (size_t)BB*64*4;
    float* bnScale = (float*)w; w += (size_t)BB*64*4;
    float* pSum = (float*)w;   w += (size_t)BB*32*64*4;
    float* pSq = (float*)w;    w += (size_t)BB*32*64*4;
    float* mo = (float*)w;     w += (size_t)PB*256*4;       // 6.1 MB, per-batch reuse
    float* logits = (float*)w;                    // 98.3 MB, per-batch reuse
    // pV/pI alias logits: score+merge fully complete (stream-ordered) before
    // k_logits writes this region. 2*32*6000*4*4B*2 = 12.3 MB << 98.3 MB.
    float* pV = logits;
    int*   pI = (int*)(logits + (size_t)BB*NSEG*PB*KK);

    k_init_inv<<<dim3(BB*SCELLS/256), dim3(256), 0, stream>>>(inv);
    k_scatter_inv<<<dim3((BB*PB+255)/256), dim3(256), 0, stream>>>(coords, inv);
    k_score_topk<<<dim3((PB+511)/512, BB, NSEG), dim3(256), 0, stream>>>(pillars, points, pV, pI);
    k_merge<<<dim3((BB*PB+255)/256), dim3(256), 0, stream>>>(pV, pI, idx);
    for (int b = 0; b < BB; b++) {
        k_logits<<<dim3(NROWS/64, 4), dim3(256), 0, stream>>>(points, idx, memw, logits, b);
        k_moG<<<dim3(PB/MOP), dim3(256), 0, stream>>>(logits, memw, mo, b);
        k_adapt<<<dim3(PB/12), dim3(256), 0, stream>>>(mo, adaptw, h, b);
    }
    k_bn1<<<dim3(BB*32), dim3(256), 0, stream>>>(h, pSum, pSq);
    k_bn2<<<dim3(BB), dim3(64), 0, stream>>>(pSum, pSq, gamma, bnMu, bnScale);
    k_fill<<<dim3(SCELLS/256, BB), dim3(256), 0, stream>>>(inv, pillars, h, bnMu, bnScale, beta, out);
}

// Round 12
// 775.091 us; speedup vs baseline: 1.1777x; 1.1297x over previous
//
#include <hip/hip_runtime.h>

#define NXg 432
#define NYg 496
#define SCELLS (NXg*NYg)   // 214272
#define PB 6000
#define NPTS 4096
#define DD 64
#define MM 1024
#define KK 4
#define BB 2
#define NROWS (PB*KK)      // 24000
#define NSEG 16
#define SEGPTS (NPTS/NSEG) // 256 points per segment
#define CHROWS 64          // point rows staged per LDS chunk
#define NCHNK (SEGPTS/CHROWS) // 4 chunks
#define MOP 6              // pillars per k_moG block
#define SHRINK_TH 0.0025f
#define BN_EPS 1e-3f
#define NEG_INF -3.402823466e38f

// sorted-descending top-4 insert on NAMED scalars; caller guarantees v > v3.
// Scans are ascending-index, so strict > keeps earliest index on ties.
#define INS4(v, id, v0,v1,v2,v3, i0,i1,i2,i3) { \
    bool g0 = (v) > v0, g1 = (v) > v1, g2 = (v) > v2; \
    v3 = g2 ? v2 : (v);              i3 = g2 ? i2 : (id); \
    v2 = g2 ? (g1 ? v1 : (v)) : v2;  i2 = g2 ? (g1 ? i1 : (id)) : i2; \
    v1 = g1 ? (g0 ? v0 : (v)) : v1;  i1 = g1 ? (g0 ? i0 : (id)) : i1; \
    v0 = g0 ? (v) : v0;              i0 = g0 ? (id) : i0; \
}

// ---------------- inverse map ----------------
__global__ __launch_bounds__(256) void k_init_inv(int* __restrict__ inv) {
    int i = blockIdx.x*256 + threadIdx.x;
    inv[i] = -1;
}

__global__ __launch_bounds__(256) void k_scatter_inv(const int* __restrict__ coords,
                                                     int* __restrict__ inv) {
    int i = blockIdx.x*256 + threadIdx.x;
    if (i >= BB*PB) return;
    int b = i / PB, p = i % PB;
    const int* c = coords + (size_t)i*3;
    int flat = c[0] + c[1]*NXg + c[2];
    inv[b*SCELLS + flat] = p;
}

// ---------------- score + top-4: k_logits-pattern, fused (r7 exact, 180us) ----------------
// r10/r11 post-mortem: 2-pillar/thread variants need >=148 VGPR -> only 2
// waves/SIMD fit (vs 3+ at VGPR 76) -> latency exposure cancels the halved
// LDS traffic (257us vs 180us). Reverted to the r7 form: 1 pillar/thread,
// broadcast + immediate-offset LDS reads (the no-spill codegen shape).
__global__ __launch_bounds__(256) void k_score_topk(const float* __restrict__ pillars,
                                                    const float* __restrict__ points,
                                                    float* __restrict__ pV,
                                                    int* __restrict__ pI) {
    __shared__ float4 sPt[CHROWS*16];     // 64 point rows, 16 KB
    const int b = blockIdx.y;
    const int seg = blockIdx.z;
    const int t = threadIdx.x;
    const int pillar = blockIdx.x*256 + t;
    const int prow = pillar < PB ? pillar : PB-1;
    const int j0 = seg * SEGPTS;

    const float4* pil4  = (const float4*)pillars;
    const float4* ptsB4 = (const float4*)(points + (size_t)b*NPTS*DD);

    float4 wreg[16];
    #pragma unroll
    for (int d4 = 0; d4 < 16; d4++)
        wreg[d4] = pil4[((size_t)b*PB + prow)*16 + d4];

    float tv0=NEG_INF, tv1=NEG_INF, tv2=NEG_INF, tv3=NEG_INF;
    int   ti0=0, ti1=0, ti2=0, ti3=0;

    for (int ch = 0; ch < NCHNK; ch++) {
        const float4* src = ptsB4 + (size_t)(j0 + ch*CHROWS)*16;
        for (int i = t; i < CHROWS*16; i += 256)
            sPt[i] = src[i];
        __syncthreads();

        const int jb = j0 + ch*CHROWS;
        for (int j = 0; j < CHROWS; j += 2) {
            float a0 = 0.f, a1 = 0.f;
            #pragma unroll
            for (int d4 = 0; d4 < 16; d4++) {
                float4 x0 = sPt[j*16 + d4];
                float4 x1 = sPt[(j+1)*16 + d4];
                a0 += wreg[d4].x*x0.x + wreg[d4].y*x0.y + wreg[d4].z*x0.z + wreg[d4].w*x0.w;
                a1 += wreg[d4].x*x1.x + wreg[d4].y*x1.y + wreg[d4].z*x1.z + wreg[d4].w*x1.w;
            }
            if (a0 > tv3) INS4(a0, jb+j,   tv0,tv1,tv2,tv3, ti0,ti1,ti2,ti3)
            if (a1 > tv3) INS4(a1, jb+j+1, tv0,tv1,tv2,tv3, ti0,ti1,ti2,ti3)
        }
        __syncthreads();
    }

    if (pillar < PB) {
        size_t ob = (((size_t)b*NSEG + seg)*PB + pillar)*KK;
        pV[ob+0]=tv0; pV[ob+1]=tv1; pV[ob+2]=tv2; pV[ob+3]=tv3;
        pI[ob+0]=ti0; pI[ob+1]=ti1; pI[ob+2]=ti2; pI[ob+3]=ti3;
    }
}

// ---------------- merge NSEG partial top-4 lists ----------------
__global__ __launch_bounds__(256) void k_merge(const float* __restrict__ pV,
                                               const int* __restrict__ pI,
                                               int* __restrict__ idxOut) {
    int i = blockIdx.x*256 + threadIdx.x;
    if (i >= BB*PB) return;
    int b = i / PB, p = i % PB;
    float fv0=NEG_INF, fv1=NEG_INF, fv2=NEG_INF, fv3=NEG_INF;
    int fi0=0, fi1=0, fi2=0, fi3=0;
    for (int s = 0; s < NSEG; s++) {   // ascending seg = ascending point ranges
        size_t base = (((size_t)b*NSEG + s)*PB + p)*KK;
        #pragma unroll
        for (int q = 0; q < 4; q++) {
            float v = pV[base+q];
            if (v > fv3) INS4(v, pI[base+q], fv0,fv1,fv2,fv3, fi0,fi1,fi2,fi3)
        }
    }
    idxOut[(size_t)i*KK+0]=fi0; idxOut[(size_t)i*KK+1]=fi1;
    idxOut[(size_t)i*KK+2]=fi2; idxOut[(size_t)i*KK+3]=fi3;
}

// ---------------- logits GEMM: X[24000x64] @ memw^T[64x1024] ----------------
__global__ __launch_bounds__(256) void k_logits(const float* __restrict__ points,
                                                const int* __restrict__ idxIn,
                                                const float* __restrict__ memw,
                                                float* __restrict__ logits,
                                                int b) {
    __shared__ float4 sX4[64*16];
    __shared__ int sId[64];
    const int t = threadIdx.x;
    const int lane = t & 63, wv = t >> 6;
    const int row0 = blockIdx.x * 64;
    const int cg = blockIdx.y * 256 + wv * 64;

    if (t < 64) sId[t] = idxIn[(size_t)b*NROWS + row0 + t];

    const float4* mw4 = (const float4*)memw;
    float4 wreg[16];
    #pragma unroll
    for (int d4 = 0; d4 < 16; d4++) wreg[d4] = mw4[(size_t)(cg + lane)*16 + d4];

    __syncthreads();
    const float4* ptsB4 = (const float4*)(points + (size_t)b*NPTS*DD);
    for (int i = t; i < 1024; i += 256) {
        int r = i >> 4, c = i & 15;
        sX4[i] = ptsB4[(size_t)sId[r]*16 + c];
    }
    __syncthreads();

    for (int r = 0; r < 64; r += 2) {
        float a0 = 0.f, a1 = 0.f;
        #pragma unroll
        for (int d4 = 0; d4 < 16; d4++) {
            float4 x0 = sX4[r*16 + d4];
            float4 x1 = sX4[(r+1)*16 + d4];
            a0 += wreg[d4].x*x0.x + wreg[d4].y*x0.y + wreg[d4].z*x0.z + wreg[d4].w*x0.w;
            a1 += wreg[d4].x*x1.x + wreg[d4].y*x1.y + wreg[d4].z*x1.z + wreg[d4].w*x1.w;
        }
        logits[(size_t)(row0 + r)*MM + cg + lane] = a0;
        logits[(size_t)(row0 + r + 1)*MM + cg + lane] = a1;
    }
}

// ---------------- mem-unit GEMM: stats + att-on-the-fly, writes mem_out ----------------
__global__ __launch_bounds__(256) void k_moG(const float* __restrict__ logits,
                                             const float* __restrict__ memw,
                                             float* __restrict__ mo,
                                             int b) {
    __shared__ __align__(16) char smem[22528];
    float4* sAtt4 = (float4*)smem;              // [24][16] f4 (6144 B)
    float4* sW4   = (float4*)(smem + 6144);     // [64 m][16 c4] (16384 B)
    float*  sWf   = (float*)sW4;
    __shared__ float sM[24], sRinv[24], sRsc[24];
    const int t = threadIdx.x;
    const int lane = t & 63, wv = t >> 6;
    const int p0 = blockIdx.x * MOP;
    const int row0 = p0 * 4;

    const float4* lg4 = (const float4*)logits;
    #pragma unroll
    for (int rr = 0; rr < MOP; rr++) {
        int r = wv*MOP + rr;
        size_t base = (size_t)(row0 + r)*256;
        float4 l0 = lg4[base + lane];
        float4 l1 = lg4[base + 64 + lane];
        float4 l2 = lg4[base + 128 + lane];
        float4 l3 = lg4[base + 192 + lane];
        float m = fmaxf(fmaxf(fmaxf(l0.x,l0.y),fmaxf(l0.z,l0.w)),
                 fmaxf(fmaxf(fmaxf(l1.x,l1.y),fmaxf(l1.z,l1.w)),
                 fmaxf(fmaxf(fmaxf(l2.x,l2.y),fmaxf(l2.z,l2.w)),
                       fmaxf(fmaxf(l3.x,l3.y),fmaxf(l3.z,l3.w)))));
        #pragma unroll
        for (int off = 1; off < 64; off <<= 1) m = fmaxf(m, __shfl_xor(m, off));
        l0.x=__expf(l0.x-m); l0.y=__expf(l0.y-m); l0.z=__expf(l0.z-m); l0.w=__expf(l0.w-m);
        l1.x=__expf(l1.x-m); l1.y=__expf(l1.y-m); l1.z=__expf(l1.z-m); l1.w=__expf(l1.w-m);
        l2.x=__expf(l2.x-m); l2.y=__expf(l2.y-m); l2.z=__expf(l2.z-m); l2.w=__expf(l2.w-m);
        l3.x=__expf(l3.x-m); l3.y=__expf(l3.y-m); l3.z=__expf(l3.z-m); l3.w=__expf(l3.w-m);
        float s = (l0.x+l0.y+l0.z+l0.w) + (l1.x+l1.y+l1.z+l1.w)
                + (l2.x+l2.y+l2.z+l2.w) + (l3.x+l3.y+l3.z+l3.w);
        #pragma unroll
        for (int off = 1; off < 64; off <<= 1) s += __shfl_xor(s, off);
        float rinv = 1.f / s;
        float sh = 0.f;
        {
            float e, tt;
            e=l0.x*rinv; tt=e-SHRINK_TH; sh += tt>0.f ? e*tt/(tt+1e-12f) : 0.f;
            e=l0.y*rinv; tt=e-SHRINK_TH; sh += tt>0.f ? e*tt/(tt+1e-12f) : 0.f;
            e=l0.z*rinv; tt=e-SHRINK_TH; sh += tt>0.f ? e*tt/(tt+1e-12f) : 0.f;
            e=l0.w*rinv; tt=e-SHRINK_TH; sh += tt>0.f ? e*tt/(tt+1e-12f) : 0.f;
            e=l1.x*rinv; tt=e-SHRINK_TH; sh += tt>0.f ? e*tt/(tt+1e-12f) : 0.f;
            e=l1.y*rinv; tt=e-SHRINK_TH; sh += tt>0.f ? e*tt/(tt+1e-12f) : 0.f;
            e=l1.z*rinv; tt=e-SHRINK_TH; sh += tt>0.f ? e*tt/(tt+1e-12f) : 0.f;
            e=l1.w*rinv; tt=e-SHRINK_TH; sh += tt>0.f ? e*tt/(tt+1e-12f) : 0.f;
            e=l2.x*rinv; tt=e-SHRINK_TH; sh += tt>0.f ? e*tt/(tt+1e-12f) : 0.f;
            e=l2.y*rinv; tt=e-SHRINK_TH; sh += tt>0.f ? e*tt/(tt+1e-12f) : 0.f;
            e=l2.z*rinv; tt=e-SHRINK_TH; sh += tt>0.f ? e*tt/(tt+1e-12f) : 0.f;
            e=l2.w*rinv; tt=e-SHRINK_TH; sh += tt>0.f ? e*tt/(tt+1e-12f) : 0.f;
            e=l3.x*rinv; tt=e-SHRINK_TH; sh += tt>0.f ? e*tt/(tt+1e-12f) : 0.f;
            e=l3.y*rinv; tt=e-SHRINK_TH; sh += tt>0.f ? e*tt/(tt+1e-12f) : 0.f;
            e=l3.z*rinv; tt=e-SHRINK_TH; sh += tt>0.f ? e*tt/(tt+1e-12f) : 0.f;
            e=l3.w*rinv; tt=e-SHRINK_TH; sh += tt>0.f ? e*tt/(tt+1e-12f) : 0.f;
        }
        #pragma unroll
        for (int off = 1; off < 64; off <<= 1) sh += __shfl_xor(sh, off);
        if (lane == 0) { sM[r] = m; sRinv[r] = rinv; sRsc[r] = 1.f/(sh + 1e-12f); }
    }
    __syncthreads();

    float acc[MOP];
    #pragma unroll
    for (int s=0;s<MOP;s++) acc[s]=0.f;
    const float4* mw4 = (const float4*)memw;

    for (int tile = 0; tile < 16; tile++) {
        __syncthreads();
        for (int i = t; i < 24*16; i += 256) {
            int rr = i >> 4, m4 = i & 15;
            float4 lg = lg4[(size_t)(row0 + rr)*256 + tile*16 + m4];
            float m = sM[rr], rinv = sRinv[rr], rsc = sRsc[rr];
            float4 o;
            float e, tt;
            e=__expf(lg.x-m)*rinv; tt=e-SHRINK_TH; o.x = (tt>0.f ? e*tt/(tt+1e-12f) : 0.f)*rsc;
            e=__expf(lg.y-m)*rinv; tt=e-SHRINK_TH; o.y = (tt>0.f ? e*tt/(tt+1e-12f) : 0.f)*rsc;
            e=__expf(lg.z-m)*rinv; tt=e-SHRINK_TH; o.z = (tt>0.f ? e*tt/(tt+1e-12f) : 0.f)*rsc;
            e=__expf(lg.w-m)*rinv; tt=e-SHRINK_TH; o.w = (tt>0.f ? e*tt/(tt+1e-12f) : 0.f)*rsc;
            sAtt4[rr*16 + m4] = o;
        }
        #pragma unroll 4
        for (int i = t; i < 1024; i += 256) {
            int m = i >> 4, c4 = i & 15;
            sW4[m*16 + c4] = mw4[(size_t)(tile*64 + m)*16 + c4];
        }
        __syncthreads();
        #pragma unroll 4
        for (int m4 = 0; m4 < 16; m4++) {
            float w0 = sWf[(m4*4+0)*64 + lane];
            float w1 = sWf[(m4*4+1)*64 + lane];
            float w2 = sWf[(m4*4+2)*64 + lane];
            float w3 = sWf[(m4*4+3)*64 + lane];
            #pragma unroll
            for (int s = 0; s < MOP; s++) {
                float4 a4 = sAtt4[(wv + 4*s)*16 + m4];
                acc[s] += a4.x*w0 + a4.y*w1 + a4.z*w2 + a4.w*w3;
            }
        }
    }
    // write mem_out: local row r = wv+4s -> pillar p0+(r>>2), k-quarter r&3
    #pragma unroll
    for (int s = 0; s < MOP; s++) {
        int r = wv + 4*s;
        mo[(size_t)(p0 + (r >> 2))*256 + (r & 3)*64 + lane] = acc[s];
    }
}

// ---------------- adapt: h = mem_out @ adaptw^T, k_logits-pattern ----------------
// r11 fix: old version staged adaptw (64KB swizzled LDS) for a 49-MFLOP
// kernel -> 78KB LDS, 2 blocks/CU. New: adaptw row `lane` held in registers
// in 4 K-quarters (16 f4, loop-static addresses = no-spill shape); mo rows
// broadcast from a 12KB LDS stage. No swizzle, no inner barriers.
__global__ __launch_bounds__(256) void k_adapt(const float* __restrict__ mo,
                                               const float* __restrict__ adaptw,
                                               float* __restrict__ hOut,
                                               int b) {
    __shared__ float4 sMo4[12*64];     // 12 pillar rows x 256 floats = 12 KB
    const int t = threadIdx.x;
    const int lane = t & 63, wv = t >> 6;
    const int p0 = blockIdx.x * 12;

    const float4* mo4 = (const float4*)(mo + (size_t)p0*256);
    #pragma unroll
    for (int q = 0; q < 3; q++)
        sMo4[q*256 + t] = mo4[q*256 + t];
    __syncthreads();

    const float4* adG4 = (const float4*)adaptw;
    float h0 = 0.f, h1 = 0.f, h2 = 0.f;   // pillars wv, wv+4, wv+8; col = lane
    #pragma unroll
    for (int qt = 0; qt < 4; qt++) {
        float4 wreg[16];
        #pragma unroll
        for (int i = 0; i < 16; i++)
            wreg[i] = adG4[(size_t)lane*64 + qt*16 + i];
        #pragma unroll
        for (int i = 0; i < 16; i++) {
            float4 q0 = sMo4[(wv+0)*64 + qt*16 + i];
            float4 q1 = sMo4[(wv+4)*64 + qt*16 + i];
            float4 q2 = sMo4[(wv+8)*64 + qt*16 + i];
            h0 += wreg[i].x*q0.x + wreg[i].y*q0.y + wreg[i].z*q0.z + wreg[i].w*q0.w;
            h1 += wreg[i].x*q1.x + wreg[i].y*q1.y + wreg[i].z*q1.z + wreg[i].w*q1.w;
            h2 += wreg[i].x*q2.x + wreg[i].y*q2.y + wreg[i].z*q2.z + wreg[i].w*q2.w;
        }
    }
    hOut[((size_t)b*PB + p0 + wv + 0)*DD + lane] = h0;
    hOut[((size_t)b*PB + p0 + wv + 4)*DD + lane] = h1;
    hOut[((size_t)b*PB + p0 + wv + 8)*DD + lane] = h2;
}

// ---------------- batchnorm stats, two-stage ----------------
__global__ __launch_bounds__(256) void k_bn1(const float* __restrict__ h,
                                             float* __restrict__ pSum,
                                             float* __restrict__ pSq) {
    const int bid = blockIdx.x;
    const int b = bid >> 5, ch = bid & 31;
    const int r0 = ch*188;
    int r1 = r0 + 188; if (r1 > PB) r1 = PB;
    __shared__ float sS[4*64], sS2[4*64];
    const int t = threadIdx.x;
    const int c = t & 63, stripe = t >> 6;
    float s = 0.f, s2 = 0.f;
    for (int r = r0 + stripe; r < r1; r += 4) {
        float v = h[((size_t)b*PB + r)*DD + c];
        s += v; s2 += v*v;
    }
    sS[stripe*64 + c] = s; sS2[stripe*64 + c] = s2;
    __syncthreads();
    if (t < 64) {
        float ts = sS[t] + sS[64+t] + sS[128+t] + sS[192+t];
        float ts2 = sS2[t] + sS2[64+t] + sS2[128+t] + sS2[192+t];
        pSum[(size_t)bid*64 + t] = ts;
        pSq[(size_t)bid*64 + t] = ts2;
    }
}

__global__ __launch_bounds__(64) void k_bn2(const float* __restrict__ pSum,
                                            const float* __restrict__ pSq,
                                            const float* __restrict__ gamma,
                                            float* __restrict__ bnMu,
                                            float* __restrict__ bnScale) {
    const int b = blockIdx.x;
    const int t = threadIdx.x;
    float ts = 0.f, ts2 = 0.f;
    for (int ch = 0; ch < 32; ch++) {
        ts += pSum[(size_t)(b*32 + ch)*64 + t];
        ts2 += pSq[(size_t)(b*32 + ch)*64 + t];
    }
    float mu = ts / (float)PB;
    float var = ts2 / (float)PB - mu*mu;
    if (var < 0.f) var = 0.f;
    bnMu[b*64+t] = mu;
    bnScale[b*64+t] = gamma[t] / sqrtf(var + BN_EPS);
}

// ---------------- dense fill (gather) ----------------
__global__ __launch_bounds__(256) void k_fill(const int* __restrict__ inv,
                                              const float* __restrict__ pillars,
                                              const float* __restrict__ h,
                                              const float* __restrict__ bnMu,
                                              const float* __restrict__ bnScale,
                                              const float* __restrict__ beta,
                                              float* __restrict__ out) {
    const int b = blockIdx.y;
    const int f = blockIdx.x*256 + threadIdx.x;
    __shared__ float sMu[64], sSc[64], sBe[64];
    if (threadIdx.x < 64) {
        sMu[threadIdx.x] = bnMu[b*64+threadIdx.x];
        sSc[threadIdx.x] = bnScale[b*64+threadIdx.x];
        sBe[threadIdx.x] = beta[threadIdx.x];
    }
    __syncthreads();
    int iv = inv[b*SCELLS + f];
    bool occ = iv >= 0;
    int iv0 = occ ? iv : 0;
    float* sp = out + (size_t)b*128*SCELLS;
    const float* prow = pillars + ((size_t)b*PB + iv0)*DD;
    const float* hrow = h + ((size_t)b*PB + iv0)*DD;
    #pragma unroll 4
    for (int c = 0; c < 64; c++)
        sp[(size_t)c*SCELLS + f] = occ ? prow[c] : 0.f;
    #pragma unroll 4
    for (int c = 0; c < 64; c++) {
        float v = 0.f;
        if (occ) {
            float hv = hrow[c];
            v = fmaxf((hv - sMu[c])*sSc[c] + sBe[c], 0.f);
        }
        sp[(size_t)(64+c)*SCELLS + f] = v;
    }
    float* pi = out + (size_t)BB*128*SCELLS + (size_t)b*3*SCELLS;
    pi[f]              = occ ? (float)(f / NXg) : 0.f;
    pi[SCELLS + f]     = occ ? (float)(f % NXg) : 0.f;
    pi[2*(size_t)SCELLS + f] = 0.f;
}

extern "C" void kernel_launch(void* const* d_in, const int* in_sizes, int n_in,
                              void* d_out, int out_size, void* d_ws, size_t ws_size,
                              hipStream_t stream) {
    const float* pillars = (const float*)d_in[0];
    const float* points  = (const float*)d_in[1];
    const int*   coords  = (const int*)d_in[2];
    const float* adaptw  = (const float*)d_in[3];
    const float* memw    = (const float*)d_in[4];
    const float* gamma   = (const float*)d_in[5];
    const float* beta    = (const float*)d_in[6];
    float* out = (float*)d_out;

    char* w = (char*)d_ws;
    int* inv = (int*)w;        w += (size_t)BB*SCELLS*4;
    int* idx = (int*)w;        w += (size_t)BB*PB*KK*4;
    float* h = (float*)w;      w += (size_t)BB*PB*DD*4;
    float* bnMu = (float*)w;   w += (size_t)BB*64*4;
    float* bnScale = (float*)w; w += (size_t)BB*64*4;
    float* pSum = (float*)w;   w += (size_t)BB*32*64*4;
    float* pSq = (float*)w;    w += (size_t)BB*32*64*4;
    float* mo = (float*)w;     w += (size_t)PB*256*4;       // 6.1 MB, per-batch reuse
    float* logits = (float*)w;                    // 98.3 MB, per-batch reuse
    // pV/pI alias logits: score+merge fully complete (stream-ordered) before
    // k_logits writes this region. 2*16*6000*4*4B*2 = 6.1 MB << 98.3 MB.
    float* pV = logits;
    int*   pI = (int*)(logits + (size_t)BB*NSEG*PB*KK);

    k_init_inv<<<dim3(BB*SCELLS/256), dim3(256), 0, stream>>>(inv);
    k_scatter_inv<<<dim3((BB*PB+255)/256), dim3(256), 0, stream>>>(coords, inv);
    k_score_topk<<<dim3((PB+255)/256, BB, NSEG), dim3(256), 0, stream>>>(pillars, points, pV, pI);
    k_merge<<<dim3((BB*PB+255)/256), dim3(256), 0, stream>>>(pV, pI, idx);
    for (int b = 0; b < BB; b++) {
        k_logits<<<dim3(NROWS/64, 4), dim3(256), 0, stream>>>(points, idx, memw, logits, b);
        k_moG<<<dim3(PB/MOP), dim3(256), 0, stream>>>(logits, memw, mo, b);
        k_adapt<<<dim3(PB/12), dim3(256), 0, stream>>>(mo, adaptw, h, b);
    }
    k_bn1<<<dim3(BB*32), dim3(256), 0, stream>>>(h, pSum, pSq);
    k_bn2<<<dim3(BB), dim3(64), 0, stream>>>(pSum, pSq, gamma, bnMu, bnScale);
    k_fill<<<dim3(SCELLS/256, BB), dim3(256), 0, stream>>>(inv, pillars, h, bnMu, bnScale, beta, out);
}

// Round 13
// 626.625 us; speedup vs baseline: 1.4567x; 1.2369x over previous
//
#include <hip/hip_runtime.h>

#define NXg 432
#define NYg 496
#define SCELLS (NXg*NYg)   // 214272
#define PB 6000
#define NPTS 4096
#define DD 64
#define MM 1024
#define KK 4
#define BB 2
#define NROWS (PB*KK)      // 24000
#define NSEG 16
#define SEGPTS (NPTS/NSEG) // 256 points per segment
#define CHROWS 64          // point rows staged per LDS chunk
#define NCHNK (SEGPTS/CHROWS) // 4 chunks
#define AR 32              // att rows per k_attg block
#define SHRINK_TH 0.0025f
#define BN_EPS 1e-3f
#define NEG_INF -3.402823466e38f

// sorted-descending top-4 insert on NAMED scalars; caller guarantees v > v3.
// Scans are ascending-index, so strict > keeps earliest index on ties.
#define INS4(v, id, v0,v1,v2,v3, i0,i1,i2,i3) { \
    bool g0 = (v) > v0, g1 = (v) > v1, g2 = (v) > v2; \
    v3 = g2 ? v2 : (v);              i3 = g2 ? i2 : (id); \
    v2 = g2 ? (g1 ? v1 : (v)) : v2;  i2 = g2 ? (g1 ? i1 : (id)) : i2; \
    v1 = g1 ? (g0 ? v0 : (v)) : v1;  i1 = g1 ? (g0 ? i0 : (id)) : i1; \
    v0 = g0 ? (v) : v0;              i0 = g0 ? (id) : i0; \
}

// ---------------- inverse map ----------------
__global__ __launch_bounds__(256) void k_init_inv(int* __restrict__ inv) {
    int i = blockIdx.x*256 + threadIdx.x;
    inv[i] = -1;
}

__global__ __launch_bounds__(256) void k_scatter_inv(const int* __restrict__ coords,
                                                     int* __restrict__ inv) {
    int i = blockIdx.x*256 + threadIdx.x;
    if (i >= BB*PB) return;
    int b = i / PB, p = i % PB;
    const int* c = coords + (size_t)i*3;
    int flat = c[0] + c[1]*NXg + c[2];
    inv[b*SCELLS + flat] = p;
}

// ---------------- score + top-4: k_logits-pattern, fused (r7 exact, 180us) ----------------
__global__ __launch_bounds__(256) void k_score_topk(const float* __restrict__ pillars,
                                                    const float* __restrict__ points,
                                                    float* __restrict__ pV,
                                                    int* __restrict__ pI) {
    __shared__ float4 sPt[CHROWS*16];     // 64 point rows, 16 KB
    const int b = blockIdx.y;
    const int seg = blockIdx.z;
    const int t = threadIdx.x;
    const int pillar = blockIdx.x*256 + t;
    const int prow = pillar < PB ? pillar : PB-1;
    const int j0 = seg * SEGPTS;

    const float4* pil4  = (const float4*)pillars;
    const float4* ptsB4 = (const float4*)(points + (size_t)b*NPTS*DD);

    float4 wreg[16];
    #pragma unroll
    for (int d4 = 0; d4 < 16; d4++)
        wreg[d4] = pil4[((size_t)b*PB + prow)*16 + d4];

    float tv0=NEG_INF, tv1=NEG_INF, tv2=NEG_INF, tv3=NEG_INF;
    int   ti0=0, ti1=0, ti2=0, ti3=0;

    for (int ch = 0; ch < NCHNK; ch++) {
        const float4* src = ptsB4 + (size_t)(j0 + ch*CHROWS)*16;
        for (int i = t; i < CHROWS*16; i += 256)
            sPt[i] = src[i];
        __syncthreads();

        const int jb = j0 + ch*CHROWS;
        for (int j = 0; j < CHROWS; j += 2) {
            float a0 = 0.f, a1 = 0.f;
            #pragma unroll
            for (int d4 = 0; d4 < 16; d4++) {
                float4 x0 = sPt[j*16 + d4];
                float4 x1 = sPt[(j+1)*16 + d4];
                a0 += wreg[d4].x*x0.x + wreg[d4].y*x0.y + wreg[d4].z*x0.z + wreg[d4].w*x0.w;
                a1 += wreg[d4].x*x1.x + wreg[d4].y*x1.y + wreg[d4].z*x1.z + wreg[d4].w*x1.w;
            }
            if (a0 > tv3) INS4(a0, jb+j,   tv0,tv1,tv2,tv3, ti0,ti1,ti2,ti3)
            if (a1 > tv3) INS4(a1, jb+j+1, tv0,tv1,tv2,tv3, ti0,ti1,ti2,ti3)
        }
        __syncthreads();
    }

    if (pillar < PB) {
        size_t ob = (((size_t)b*NSEG + seg)*PB + pillar)*KK;
        pV[ob+0]=tv0; pV[ob+1]=tv1; pV[ob+2]=tv2; pV[ob+3]=tv3;
        pI[ob+0]=ti0; pI[ob+1]=ti1; pI[ob+2]=ti2; pI[ob+3]=ti3;
    }
}

// ---------------- merge NSEG partial top-4 lists ----------------
__global__ __launch_bounds__(256) void k_merge(const float* __restrict__ pV,
                                               const int* __restrict__ pI,
                                               int* __restrict__ idxOut) {
    int i = blockIdx.x*256 + threadIdx.x;
    if (i >= BB*PB) return;
    int b = i / PB, p = i % PB;
    float fv0=NEG_INF, fv1=NEG_INF, fv2=NEG_INF, fv3=NEG_INF;
    int fi0=0, fi1=0, fi2=0, fi3=0;
    for (int s = 0; s < NSEG; s++) {   // ascending seg = ascending point ranges
        size_t base = (((size_t)b*NSEG + s)*PB + p)*KK;
        #pragma unroll
        for (int q = 0; q < 4; q++) {
            float v = pV[base+q];
            if (v > fv3) INS4(v, pI[base+q], fv0,fv1,fv2,fv3, fi0,fi1,fi2,fi3)
        }
    }
    idxOut[(size_t)i*KK+0]=fi0; idxOut[(size_t)i*KK+1]=fi1;
    idxOut[(size_t)i*KK+2]=fi2; idxOut[(size_t)i*KK+3]=fi3;
}

// ---------------- logits GEMM: X[24000x64] @ memw^T[64x1024] ----------------
__global__ __launch_bounds__(256) void k_logits(const float* __restrict__ points,
                                                const int* __restrict__ idxIn,
                                                const float* __restrict__ memw,
                                                float* __restrict__ logits,
                                                int b) {
    __shared__ float4 sX4[64*16];
    __shared__ int sId[64];
    const int t = threadIdx.x;
    const int lane = t & 63, wv = t >> 6;
    const int row0 = blockIdx.x * 64;
    const int cg = blockIdx.y * 256 + wv * 64;

    if (t < 64) sId[t] = idxIn[(size_t)b*NROWS + row0 + t];

    const float4* mw4 = (const float4*)memw;
    float4 wreg[16];
    #pragma unroll
    for (int d4 = 0; d4 < 16; d4++) wreg[d4] = mw4[(size_t)(cg + lane)*16 + d4];

    __syncthreads();
    const float4* ptsB4 = (const float4*)(points + (size_t)b*NPTS*DD);
    for (int i = t; i < 1024; i += 256) {
        int r = i >> 4, c = i & 15;
        sX4[i] = ptsB4[(size_t)sId[r]*16 + c];
    }
    __syncthreads();

    for (int r = 0; r < 64; r += 2) {
        float a0 = 0.f, a1 = 0.f;
        #pragma unroll
        for (int d4 = 0; d4 < 16; d4++) {
            float4 x0 = sX4[r*16 + d4];
            float4 x1 = sX4[(r+1)*16 + d4];
            a0 += wreg[d4].x*x0.x + wreg[d4].y*x0.y + wreg[d4].z*x0.z + wreg[d4].w*x0.w;
            a1 += wreg[d4].x*x1.x + wreg[d4].y*x1.y + wreg[d4].z*x1.z + wreg[d4].w*x1.w;
        }
        logits[(size_t)(row0 + r)*MM + cg + lane] = a0;
        logits[(size_t)(row0 + r + 1)*MM + cg + lane] = a1;
    }
}

// ---------------- row stats: m, 1/expsum, 1/shrinksum per logits row (r8, proven) ----------------
__global__ __launch_bounds__(256) void k_stats(const float* __restrict__ logits,
                                               float* __restrict__ stats,
                                               int b) {
    const int wv = threadIdx.x >> 6, lane = threadIdx.x & 63;
    const int row = blockIdx.x*4 + wv;
    const float4* lg4 = (const float4*)logits;
    size_t base = (size_t)row*256;
    float4 l0 = lg4[base + lane];
    float4 l1 = lg4[base + 64 + lane];
    float4 l2 = lg4[base + 128 + lane];
    float4 l3 = lg4[base + 192 + lane];
    float m = fmaxf(fmaxf(fmaxf(l0.x,l0.y),fmaxf(l0.z,l0.w)),
             fmaxf(fmaxf(fmaxf(l1.x,l1.y),fmaxf(l1.z,l1.w)),
             fmaxf(fmaxf(fmaxf(l2.x,l2.y),fmaxf(l2.z,l2.w)),
                   fmaxf(fmaxf(l3.x,l3.y),fmaxf(l3.z,l3.w)))));
    #pragma unroll
    for (int off = 1; off < 64; off <<= 1) m = fmaxf(m, __shfl_xor(m, off));
    l0.x=__expf(l0.x-m); l0.y=__expf(l0.y-m); l0.z=__expf(l0.z-m); l0.w=__expf(l0.w-m);
    l1.x=__expf(l1.x-m); l1.y=__expf(l1.y-m); l1.z=__expf(l1.z-m); l1.w=__expf(l1.w-m);
    l2.x=__expf(l2.x-m); l2.y=__expf(l2.y-m); l2.z=__expf(l2.z-m); l2.w=__expf(l2.w-m);
    l3.x=__expf(l3.x-m); l3.y=__expf(l3.y-m); l3.z=__expf(l3.z-m); l3.w=__expf(l3.w-m);
    float s = (l0.x+l0.y+l0.z+l0.w) + (l1.x+l1.y+l1.z+l1.w)
            + (l2.x+l2.y+l2.z+l2.w) + (l3.x+l3.y+l3.z+l3.w);
    #pragma unroll
    for (int off = 1; off < 64; off <<= 1) s += __shfl_xor(s, off);
    float rinv = 1.f / s;
    float sh = 0.f;
    {
        float e, tt;
        e=l0.x*rinv; tt=e-SHRINK_TH; sh += tt>0.f ? e*tt/(tt+1e-12f) : 0.f;
        e=l0.y*rinv; tt=e-SHRINK_TH; sh += tt>0.f ? e*tt/(tt+1e-12f) : 0.f;
        e=l0.z*rinv; tt=e-SHRINK_TH; sh += tt>0.f ? e*tt/(tt+1e-12f) : 0.f;
        e=l0.w*rinv; tt=e-SHRINK_TH; sh += tt>0.f ? e*tt/(tt+1e-12f) : 0.f;
        e=l1.x*rinv; tt=e-SHRINK_TH; sh += tt>0.f ? e*tt/(tt+1e-12f) : 0.f;
        e=l1.y*rinv; tt=e-SHRINK_TH; sh += tt>0.f ? e*tt/(tt+1e-12f) : 0.f;
        e=l1.z*rinv; tt=e-SHRINK_TH; sh += tt>0.f ? e*tt/(tt+1e-12f) : 0.f;
        e=l1.w*rinv; tt=e-SHRINK_TH; sh += tt>0.f ? e*tt/(tt+1e-12f) : 0.f;
        e=l2.x*rinv; tt=e-SHRINK_TH; sh += tt>0.f ? e*tt/(tt+1e-12f) : 0.f;
        e=l2.y*rinv; tt=e-SHRINK_TH; sh += tt>0.f ? e*tt/(tt+1e-12f) : 0.f;
        e=l2.z*rinv; tt=e-SHRINK_TH; sh += tt>0.f ? e*tt/(tt+1e-12f) : 0.f;
        e=l2.w*rinv; tt=e-SHRINK_TH; sh += tt>0.f ? e*tt/(tt+1e-12f) : 0.f;
        e=l3.x*rinv; tt=e-SHRINK_TH; sh += tt>0.f ? e*tt/(tt+1e-12f) : 0.f;
        e=l3.y*rinv; tt=e-SHRINK_TH; sh += tt>0.f ? e*tt/(tt+1e-12f) : 0.f;
        e=l3.z*rinv; tt=e-SHRINK_TH; sh += tt>0.f ? e*tt/(tt+1e-12f) : 0.f;
        e=l3.w*rinv; tt=e-SHRINK_TH; sh += tt>0.f ? e*tt/(tt+1e-12f) : 0.f;
    }
    #pragma unroll
    for (int off = 1; off < 64; off <<= 1) sh += __shfl_xor(sh, off);
    if (lane == 0) {
        float4* st4 = (float4*)stats;
        st4[(size_t)b*NROWS + row] = make_float4(m, rinv, 1.f/(sh + 1e-12f), 0.f);
    }
}

// ---------------- att GEMM: mem_out = shr(att) @ memw, 2x4 microtile ----------------
// r12 post-mortem: k_moG's GEMM was LDS-return-bound (per m4: 4 b32 + 6 b128
// = ~95 cyc LDS vs 48 cyc FMA; invariant to occupancy across 3 variants).
// Rebalance: thread = 2 rows x 4 cols. Per m4: 2 att b128 + 4 w b128 = 72
// cyc LDS vs 32 FMA = 64 cyc VALU -> parity. att tile staged with row
// stride 68 floats (rg groups hit disjoint banks: 136 words = 8 mod 32);
// w tile [64m][64c] plain (cg*4-word reads 2-way = free). All LDS reads
// base + immediate offsets (the no-spill shape). Stats via k_stats.
// Block = 32 rows -> grid 750/batch ~ 3 blocks/CU.
__global__ __launch_bounds__(256) void k_attg(const float* __restrict__ logits,
                                              const float* __restrict__ memw,
                                              const float* __restrict__ stats,
                                              float* __restrict__ mo,
                                              int b) {
    __shared__ __align__(16) float sAtt[AR*68];   // [32 rows][16 f4 + 1 f4 pad] 8704 B
    __shared__ __align__(16) float4 sW4[64*16];   // [64 m][64 c] 16 KB
    __shared__ float sSt[AR*4];
    const int t = threadIdx.x;
    const int cg = t & 15, rg = t >> 4;           // 16 col-groups x 16 row-groups
    const int row0 = blockIdx.x * AR;

    if (t < AR) {
        const float4* st4 = (const float4*)stats;
        float4 s = st4[(size_t)b*NROWS + row0 + t];
        sSt[t*4+0]=s.x; sSt[t*4+1]=s.y; sSt[t*4+2]=s.z; sSt[t*4+3]=s.w;
    }
    __syncthreads();

    const float4* lg4 = (const float4*)logits;
    const float4* mw4 = (const float4*)memw;
    float4 acc0 = make_float4(0.f,0.f,0.f,0.f);
    float4 acc1 = make_float4(0.f,0.f,0.f,0.f);

    for (int tile = 0; tile < 16; tile++) {
        // ---- stage att chunk [32 rows][64 m] (512 f4, 2/thread) ----
        #pragma unroll
        for (int q = 0; q < 2; q++) {
            int idx = q*256 + t;
            int row = idx >> 4, m4 = idx & 15;
            float4 lg = lg4[(size_t)(row0 + row)*256 + tile*16 + m4];
            float m = sSt[row*4], rinv = sSt[row*4+1], rsc = sSt[row*4+2];
            float4 o; float e, tt;
            e=__expf(lg.x-m)*rinv; tt=e-SHRINK_TH; o.x=(tt>0.f?e*tt/(tt+1e-12f):0.f)*rsc;
            e=__expf(lg.y-m)*rinv; tt=e-SHRINK_TH; o.y=(tt>0.f?e*tt/(tt+1e-12f):0.f)*rsc;
            e=__expf(lg.z-m)*rinv; tt=e-SHRINK_TH; o.z=(tt>0.f?e*tt/(tt+1e-12f):0.f)*rsc;
            e=__expf(lg.w-m)*rinv; tt=e-SHRINK_TH; o.w=(tt>0.f?e*tt/(tt+1e-12f):0.f)*rsc;
            *(float4*)(sAtt + row*68 + m4*4) = o;
        }
        // ---- stage w chunk [64 m][64 c] (1024 f4, 4/thread) ----
        #pragma unroll
        for (int q = 0; q < 4; q++) {
            int idx = q*256 + t;
            sW4[idx] = mw4[(size_t)tile*1024 + idx];
        }
        __syncthreads();
        // ---- GEMM: 2 rows x 4 cols per thread ----
        #pragma unroll 4
        for (int m4 = 0; m4 < 16; m4++) {
            float4 a0 = *(const float4*)(sAtt + (rg*2+0)*68 + m4*4);
            float4 a1 = *(const float4*)(sAtt + (rg*2+1)*68 + m4*4);
            float4 w0 = sW4[(m4*4+0)*16 + cg];
            float4 w1 = sW4[(m4*4+1)*16 + cg];
            float4 w2 = sW4[(m4*4+2)*16 + cg];
            float4 w3 = sW4[(m4*4+3)*16 + cg];
            acc0.x += a0.x*w0.x + a0.y*w1.x + a0.z*w2.x + a0.w*w3.x;
            acc0.y += a0.x*w0.y + a0.y*w1.y + a0.z*w2.y + a0.w*w3.y;
            acc0.z += a0.x*w0.z + a0.y*w1.z + a0.z*w2.z + a0.w*w3.z;
            acc0.w += a0.x*w0.w + a0.y*w1.w + a0.z*w2.w + a0.w*w3.w;
            acc1.x += a1.x*w0.x + a1.y*w1.x + a1.z*w2.x + a1.w*w3.x;
            acc1.y += a1.x*w0.y + a1.y*w1.y + a1.z*w2.y + a1.w*w3.y;
            acc1.z += a1.x*w0.z + a1.y*w1.z + a1.z*w2.z + a1.w*w3.z;
            acc1.w += a1.x*w0.w + a1.y*w1.w + a1.z*w2.w + a1.w*w3.w;
        }
        __syncthreads();   // tile consumed before next stage overwrites
    }

    // mo is row-major [NROWS][64]
    *(float4*)(mo + (size_t)(row0 + rg*2 + 0)*64 + cg*4) = acc0;
    *(float4*)(mo + (size_t)(row0 + rg*2 + 1)*64 + cg*4) = acc1;
}

// ---------------- adapt: h = mem_out @ adaptw^T, k_logits-pattern (r12) ----------------
__global__ __launch_bounds__(256) void k_adapt(const float* __restrict__ mo,
                                               const float* __restrict__ adaptw,
                                               float* __restrict__ hOut,
                                               int b) {
    __shared__ float4 sMo4[12*64];     // 12 pillar rows x 256 floats = 12 KB
    const int t = threadIdx.x;
    const int lane = t & 63, wv = t >> 6;
    const int p0 = blockIdx.x * 12;

    const float4* mo4 = (const float4*)(mo + (size_t)p0*256);
    #pragma unroll
    for (int q = 0; q < 3; q++)
        sMo4[q*256 + t] = mo4[q*256 + t];
    __syncthreads();

    const float4* adG4 = (const float4*)adaptw;
    float h0 = 0.f, h1 = 0.f, h2 = 0.f;   // pillars wv, wv+4, wv+8; col = lane
    #pragma unroll
    for (int qt = 0; qt < 4; qt++) {
        float4 wreg[16];
        #pragma unroll
        for (int i = 0; i < 16; i++)
            wreg[i] = adG4[(size_t)lane*64 + qt*16 + i];
        #pragma unroll
        for (int i = 0; i < 16; i++) {
            float4 q0 = sMo4[(wv+0)*64 + qt*16 + i];
            float4 q1 = sMo4[(wv+4)*64 + qt*16 + i];
            float4 q2 = sMo4[(wv+8)*64 + qt*16 + i];
            h0 += wreg[i].x*q0.x + wreg[i].y*q0.y + wreg[i].z*q0.z + wreg[i].w*q0.w;
            h1 += wreg[i].x*q1.x + wreg[i].y*q1.y + wreg[i].z*q1.z + wreg[i].w*q1.w;
            h2 += wreg[i].x*q2.x + wreg[i].y*q2.y + wreg[i].z*q2.z + wreg[i].w*q2.w;
        }
    }
    hOut[((size_t)b*PB + p0 + wv + 0)*DD + lane] = h0;
    hOut[((size_t)b*PB + p0 + wv + 4)*DD + lane] = h1;
    hOut[((size_t)b*PB + p0 + wv + 8)*DD + lane] = h2;
}

// ---------------- batchnorm stats, two-stage ----------------
__global__ __launch_bounds__(256) void k_bn1(const float* __restrict__ h,
                                             float* __restrict__ pSum,
                                             float* __restrict__ pSq) {
    const int bid = blockIdx.x;
    const int b = bid >> 5, ch = bid & 31;
    const int r0 = ch*188;
    int r1 = r0 + 188; if (r1 > PB) r1 = PB;
    __shared__ float sS[4*64], sS2[4*64];
    const int t = threadIdx.x;
    const int c = t & 63, stripe = t >> 6;
    float s = 0.f, s2 = 0.f;
    for (int r = r0 + stripe; r < r1; r += 4) {
        float v = h[((size_t)b*PB + r)*DD + c];
        s += v; s2 += v*v;
    }
    sS[stripe*64 + c] = s; sS2[stripe*64 + c] = s2;
    __syncthreads();
    if (t < 64) {
        float ts = sS[t] + sS[64+t] + sS[128+t] + sS[192+t];
        float ts2 = sS2[t] + sS2[64+t] + sS2[128+t] + sS2[192+t];
        pSum[(size_t)bid*64 + t] = ts;
        pSq[(size_t)bid*64 + t] = ts2;
    }
}

__global__ __launch_bounds__(64) void k_bn2(const float* __restrict__ pSum,
                                            const float* __restrict__ pSq,
                                            const float* __restrict__ gamma,
                                            float* __restrict__ bnMu,
                                            float* __restrict__ bnScale) {
    const int b = blockIdx.x;
    const int t = threadIdx.x;
    float ts = 0.f, ts2 = 0.f;
    for (int ch = 0; ch < 32; ch++) {
        ts += pSum[(size_t)(b*32 + ch)*64 + t];
        ts2 += pSq[(size_t)(b*32 + ch)*64 + t];
    }
    float mu = ts / (float)PB;
    float var = ts2 / (float)PB - mu*mu;
    if (var < 0.f) var = 0.f;
    bnMu[b*64+t] = mu;
    bnScale[b*64+t] = gamma[t] / sqrtf(var + BN_EPS);
}

// ---------------- dense fill (gather) ----------------
__global__ __launch_bounds__(256) void k_fill(const int* __restrict__ inv,
                                              const float* __restrict__ pillars,
                                              const float* __restrict__ h,
                                              const float* __restrict__ bnMu,
                                              const float* __restrict__ bnScale,
                                              const float* __restrict__ beta,
                                              float* __restrict__ out) {
    const int b = blockIdx.y;
    const int f = blockIdx.x*256 + threadIdx.x;
    __shared__ float sMu[64], sSc[64], sBe[64];
    if (threadIdx.x < 64) {
        sMu[threadIdx.x] = bnMu[b*64+threadIdx.x];
        sSc[threadIdx.x] = bnScale[b*64+threadIdx.x];
        sBe[threadIdx.x] = beta[threadIdx.x];
    }
    __syncthreads();
    int iv = inv[b*SCELLS + f];
    bool occ = iv >= 0;
    int iv0 = occ ? iv : 0;
    float* sp = out + (size_t)b*128*SCELLS;
    const float* prow = pillars + ((size_t)b*PB + iv0)*DD;
    const float* hrow = h + ((size_t)b*PB + iv0)*DD;
    #pragma unroll 4
    for (int c = 0; c < 64; c++)
        sp[(size_t)c*SCELLS + f] = occ ? prow[c] : 0.f;
    #pragma unroll 4
    for (int c = 0; c < 64; c++) {
        float v = 0.f;
        if (occ) {
            float hv = hrow[c];
            v = fmaxf((hv - sMu[c])*sSc[c] + sBe[c], 0.f);
        }
        sp[(size_t)(64+c)*SCELLS + f] = v;
    }
    float* pi = out + (size_t)BB*128*SCELLS + (size_t)b*3*SCELLS;
    pi[f]              = occ ? (float)(f / NXg) : 0.f;
    pi[SCELLS + f]     = occ ? (float)(f % NXg) : 0.f;
    pi[2*(size_t)SCELLS + f] = 0.f;
}

extern "C" void kernel_launch(void* const* d_in, const int* in_sizes, int n_in,
                              void* d_out, int out_size, void* d_ws, size_t ws_size,
                              hipStream_t stream) {
    const float* pillars = (const float*)d_in[0];
    const float* points  = (const float*)d_in[1];
    const int*   coords  = (const int*)d_in[2];
    const float* adaptw  = (const float*)d_in[3];
    const float* memw    = (const float*)d_in[4];
    const float* gamma   = (const float*)d_in[5];
    const float* beta    = (const float*)d_in[6];
    float* out = (float*)d_out;

    char* w = (char*)d_ws;
    int* inv = (int*)w;        w += (size_t)BB*SCELLS*4;
    int* idx = (int*)w;        w += (size_t)BB*PB*KK*4;
    float* h = (float*)w;      w += (size_t)BB*PB*DD*4;
    float* bnMu = (float*)w;   w += (size_t)BB*64*4;
    float* bnScale = (float*)w; w += (size_t)BB*64*4;
    float* pSum = (float*)w;   w += (size_t)BB*32*64*4;
    float* pSq = (float*)w;    w += (size_t)BB*32*64*4;
    float* stats = (float*)w;  w += (size_t)BB*NROWS*4*4;   // 768 KB
    float* mo = (float*)w;     w += (size_t)NROWS*DD*4;     // 6.1 MB, per-batch reuse
    float* logits = (float*)w;                    // 98.3 MB, per-batch reuse
    // pV/pI alias logits: score+merge fully complete (stream-ordered) before
    // k_logits writes this region. 2*16*6000*4*4B*2 = 6.1 MB << 98.3 MB.
    float* pV = logits;
    int*   pI = (int*)(logits + (size_t)BB*NSEG*PB*KK);

    k_init_inv<<<dim3(BB*SCELLS/256), dim3(256), 0, stream>>>(inv);
    k_scatter_inv<<<dim3((BB*PB+255)/256), dim3(256), 0, stream>>>(coords, inv);
    k_score_topk<<<dim3((PB+255)/256, BB, NSEG), dim3(256), 0, stream>>>(pillars, points, pV, pI);
    k_merge<<<dim3((BB*PB+255)/256), dim3(256), 0, stream>>>(pV, pI, idx);
    for (int b = 0; b < BB; b++) {
        k_logits<<<dim3(NROWS/64, 4), dim3(256), 0, stream>>>(points, idx, memw, logits, b);
        k_stats<<<dim3(NROWS/4), dim3(256), 0, stream>>>(logits, stats, b);
        k_attg<<<dim3(NROWS/AR), dim3(256), 0, stream>>>(logits, memw, stats, mo, b);
        k_adapt<<<dim3(PB/12), dim3(256), 0, stream>>>(mo, adaptw, h, b);
    }
    k_bn1<<<dim3(BB*32), dim3(256), 0, stream>>>(h, pSum, pSq);
    k_bn2<<<dim3(BB), dim3(64), 0, stream>>>(pSum, pSq, gamma, bnMu, bnScale);
    k_fill<<<dim3(SCELLS/256, BB), dim3(256), 0, stream>>>(inv, pillars, h, bnMu, bnScale, beta, out);
}